// Round 17
// baseline (945.570 us; speedup 1.0000x reference)
//
#include <hip/hip_runtime.h>
#include <math.h>

#define BQ   64
#define NN0  2048
#define CF   128
#define ET   2097152
#define OUTF 16

// ---------- helpers ----------
static __device__ __forceinline__ unsigned f2o(float f) {
    unsigned u = __float_as_uint(f);
    return (u & 0x80000000u) ? ~u : (u | 0x80000000u);
}

// ---------- normalize p vectors ----------
__global__ void k_normp(const float* p1, const float* p2, const float* p3, float* pn) {
    const float* ps[3] = {p1, p2, p3};
    const float* p = ps[blockIdx.x];
    int t = threadIdx.x; // 128 threads
    float v = p[t];
    float s = v * v;
    for (int o = 32; o > 0; o >>= 1) s += __shfl_down(s, o);
    __shared__ float ws2[2];
    if ((t & 63) == 0) ws2[t >> 6] = s;
    __syncthreads();
    float tot = ws2[0] + ws2[1];
    pn[blockIdx.x * CF + t] = v / sqrtf(tot);
}

// ---------- GEMM: Y[N][128] = X[N][128] @ W[128][128], f32 ----------
__global__ __launch_bounds__(256, 2) void k_gemm(const float* __restrict__ X,
                                                 const float* __restrict__ W,
                                                 float* __restrict__ Y, int N) {
    __shared__ float xT[32][260];
    __shared__ float Wc[32][128];
    int t = threadIdx.x;
    int cg = t & 15, rg = t >> 4;
    int c0 = cg * 8, r0 = rg * 16;
    int rowBase = blockIdx.x * 256;

    float acc[16][8];
#pragma unroll
    for (int i = 0; i < 16; i++)
#pragma unroll
        for (int j = 0; j < 8; j++) acc[i][j] = 0.f;

    for (int kc = 0; kc < 4; kc++) {
        __syncthreads();
#pragma unroll
        for (int j = 0; j < 8; j++) {
            int id = t + 256 * j;
            int r = id >> 3;
            int k4 = id & 7;
            float4 v = *(const float4*)&X[(rowBase + r) * CF + kc * 32 + k4 * 4];
            int kk = k4 * 4;
            xT[kk + 0][r] = v.x; xT[kk + 1][r] = v.y;
            xT[kk + 2][r] = v.z; xT[kk + 3][r] = v.w;
        }
#pragma unroll
        for (int j = 0; j < 4; j++) {
            int id = t + 256 * j;
            int kk = id >> 5;
            int cc = (id & 31) * 4;
            *(float4*)&Wc[kk][cc] = *(const float4*)&W[(kc * 32 + kk) * CF + cc];
        }
        __syncthreads();
#pragma unroll 4
        for (int kk = 0; kk < 32; kk++) {
            float xr[16];
#pragma unroll
            for (int i = 0; i < 16; i += 4)
                *(float4*)&xr[i] = *(float4*)&xT[kk][r0 + i];
            float wv[8];
            *(float4*)&wv[0] = *(float4*)&Wc[kk][c0];
            *(float4*)&wv[4] = *(float4*)&Wc[kk][c0 + 4];
#pragma unroll
            for (int i = 0; i < 16; i++)
#pragma unroll
                for (int j = 0; j < 8; j++)
                    acc[i][j] = fmaf(xr[i], wv[j], acc[i][j]);
        }
    }
#pragma unroll
    for (int i = 0; i < 16; i++) {
        int r = rowBase + r0 + i;
        *(float4*)&Y[r * CF + c0]     = make_float4(acc[i][0], acc[i][1], acc[i][2], acc[i][3]);
        *(float4*)&Y[r * CF + c0 + 4] = make_float4(acc[i][4], acc[i][5], acc[i][6], acc[i][7]);
    }
}

// ---------- histograms ----------
__global__ void k_hist1(const int* __restrict__ g, const int* __restrict__ dl, int* cnt) {
    int e = blockIdx.x * 256 + threadIdx.x;
    if (e < ET) atomicAdd(&cnt[g[e] * NN0 + dl[e]], 1);
}
__global__ void k_hist2(const int2* __restrict__ edges, const int* pE, int* cnt) {
    int e = blockIdx.x * 256 + threadIdx.x;
    if (e < *pE) atomicAdd(&cnt[edges[e].y], 1);
}

// ---------- exclusive scan (3 kernels), chunk=1024 ----------
__global__ void k_ps1(const int* __restrict__ cnt, int* part) {
    int b = blockIdx.x, t = threadIdx.x;
    int base = b * 1024;
    int s = 0;
    for (int j = t; j < 1024; j += 256) s += cnt[base + j];
    for (int o = 32; o > 0; o >>= 1) s += __shfl_down(s, o);
    __shared__ int sm[4];
    if ((t & 63) == 0) sm[t >> 6] = s;
    __syncthreads();
    if (t == 0) part[b] = sm[0] + sm[1] + sm[2] + sm[3];
}
__global__ void k_ps2(int* part, int nb) {
    if (threadIdx.x == 0) {
        int run = 0;
        for (int i = 0; i < nb; i++) { int v = part[i]; part[i] = run; run += v; }
        part[nb] = run;
    }
}
// emits dis[i] = rsqrt(deg_i) (deg = cnt+1) for the agg pass.
__global__ void k_ps3(const int* __restrict__ cnt, const int* __restrict__ part,
                      int* rowS, int* curs, float* dis, int N) {
    __shared__ int sm[256];
    int b = blockIdx.x, t = threadIdx.x;
    int base = b * 1024;
    int loc[4], cv[4];
    int s = 0;
#pragma unroll
    for (int j = 0; j < 4; j++) { loc[j] = s; cv[j] = cnt[base + t * 4 + j]; s += cv[j]; }
    sm[t] = s;
    __syncthreads();
    for (int o = 1; o < 256; o <<= 1) {
        int u = (t >= o) ? sm[t - o] : 0;
        __syncthreads();
        sm[t] += u;
        __syncthreads();
    }
    int incl = sm[t];
    int thrBase = part[b] + incl - s;
#pragma unroll
    for (int j = 0; j < 4; j++) {
        int idx = base + t * 4 + j;
        rowS[idx] = thrBase + loc[j];
        curs[idx] = thrBase + loc[j];
        if (dis != nullptr) dis[idx] = rsqrtf((float)(cv[j] + 1));
    }
    if (b == gridDim.x - 1 && t == 255) rowS[N] = part[b] + incl;
}

// ---------- bucket-sorted CSR build (R15; R16 SB fix; R17 alias fix) ----------
// R14: scattered 4B stores are structurally ~15x write-amplified; fix by layout.
// binA: per-8192-edge-block LDS hist over 128-node dst buckets -> H1[blk][bkt].
// scanB: per-bucket scan of block counts + rowS[b*128] -> seg base per (bkt,blk).
// binB: re-read edges, group in LDS, flush per-bucket runs as contiguous wave
//       writes to seg (packed (dlow<<SB)|src).
// binC: one block per bucket: contiguous read, LDS counting-sort by dlow(7b),
//       fully coalesced csrS write. No curs atomics anywhere.
// R17 fix: xw1 fills ALL 64MB of A; R15 put seg1/H1a/BSa inside A -> clobbered
// xw1 rows before agg read them. Moved to Bb[0:10MB] (dead until agg1 writes h1).
__global__ void k_binA1(const int* __restrict__ g, const int* __restrict__ dl,
                        int* __restrict__ H1) {
    __shared__ int c[1024];
    int t = threadIdx.x, blk = blockIdx.x;
#pragma unroll
    for (int j = t; j < 1024; j += 256) c[j] = 0;
    __syncthreads();
    int base = blk * 8192;
#pragma unroll 4
    for (int it = 0; it < 32; it++) {
        int e = base + it * 256 + t;
        int d = g[e] * NN0 + dl[e];
        atomicAdd(&c[d >> 7], 1);
    }
    __syncthreads();
    for (int j = t; j < 1024; j += 256) H1[blk * 1024 + j] = c[j];
}
__global__ void k_binA2(const int2* __restrict__ edges, const int* pE,
                        int* __restrict__ H1, int NB) {
    __shared__ int c[1024];
    int t = threadIdx.x, blk = blockIdx.x;
    for (int j = t; j < NB; j += 256) c[j] = 0;
    __syncthreads();
    int E = *pE;
    int base = blk * 8192;
    for (int it = 0; it < 32; it++) {
        int e = base + it * 256 + t;
        if (e < E) atomicAdd(&c[edges[e].y >> 7], 1);
    }
    __syncthreads();
    for (int j = t; j < NB; j += 256) H1[blk * NB + j] = c[j];
}
// one block per bucket: scan 256 block-counts, add bucket's csrS segment base
__global__ void k_scanB(const int* __restrict__ H1, const int* __restrict__ rowS,
                        int* __restrict__ base, int NB) {
    __shared__ int sm[256];
    int b = blockIdx.x, t = threadIdx.x;
    int v = H1[t * NB + b];
    sm[t] = v;
    __syncthreads();
    for (int o = 1; o < 256; o <<= 1) {
        int u = (t >= o) ? sm[t - o] : 0;
        __syncthreads();
        sm[t] += u;
        __syncthreads();
    }
    base[b * 256 + t] = rowS[b * 128] + sm[t] - v;
}
__global__ void k_binB1(const int* __restrict__ g, const int* __restrict__ sl,
                        const int* __restrict__ dl, const int* __restrict__ H1,
                        const int* __restrict__ base, unsigned* __restrict__ seg) {
    __shared__ int c[1024], rb[1024], cur[1024];
    __shared__ unsigned out[8192];
    int t = threadIdx.x, blk = blockIdx.x;
    int l0 = H1[blk * 1024 + 4 * t], l1 = H1[blk * 1024 + 4 * t + 1];
    int l2 = H1[blk * 1024 + 4 * t + 2], l3 = H1[blk * 1024 + 4 * t + 3];
    c[4 * t] = l0; c[4 * t + 1] = l1; c[4 * t + 2] = l2; c[4 * t + 3] = l3;
    int s = l0 + l1 + l2 + l3;
    __shared__ int sm[256];
    sm[t] = s;
    __syncthreads();
    for (int o = 1; o < 256; o <<= 1) {
        int u = (t >= o) ? sm[t - o] : 0;
        __syncthreads();
        sm[t] += u;
        __syncthreads();
    }
    int ex = sm[t] - s;
    rb[4 * t] = ex; cur[4 * t] = ex;
    rb[4 * t + 1] = ex + l0; cur[4 * t + 1] = ex + l0;
    rb[4 * t + 2] = ex + l0 + l1; cur[4 * t + 2] = ex + l0 + l1;
    rb[4 * t + 3] = ex + l0 + l1 + l2; cur[4 * t + 3] = ex + l0 + l1 + l2;
    __syncthreads();
    int ebase = blk * 8192;
#pragma unroll 4
    for (int it = 0; it < 32; it++) {
        int e = ebase + it * 256 + t;
        int gg = g[e];
        int d = gg * NN0 + dl[e];
        unsigned packed = ((unsigned)(d & 127) << 17) | (unsigned)(gg * NN0 + sl[e]);
        int pos = atomicAdd(&cur[d >> 7], 1);
        out[pos] = packed;
    }
    __syncthreads();
    int w = t >> 6, lane = t & 63;
    for (int b = w; b < 1024; b += 4) {
        int cb = c[b];
        if (cb == 0) continue;
        int gb = base[b * 256 + blk];
        int rbb = rb[b];
        for (int i = lane; i < cb; i += 64) seg[gb + i] = out[rbb + i];
    }
}
__global__ void k_binB2(const int2* __restrict__ edges, const int* pE,
                        const int* __restrict__ H1, const int* __restrict__ base,
                        unsigned* __restrict__ seg, int NB, int SB) {
    __shared__ int c[1024], rb[1024], cur[1024];
    __shared__ unsigned out[8192];
    __shared__ int sm[256];
    int t = threadIdx.x, blk = blockIdx.x;
    int n4 = NB >> 2; // threads t < n4 own 4 buckets each
    int l0 = 0, l1 = 0, l2 = 0, l3 = 0;
    if (t < n4) {
        l0 = H1[blk * NB + 4 * t];     l1 = H1[blk * NB + 4 * t + 1];
        l2 = H1[blk * NB + 4 * t + 2]; l3 = H1[blk * NB + 4 * t + 3];
        c[4 * t] = l0; c[4 * t + 1] = l1; c[4 * t + 2] = l2; c[4 * t + 3] = l3;
    }
    int s = l0 + l1 + l2 + l3;
    sm[t] = s;
    __syncthreads();
    for (int o = 1; o < 256; o <<= 1) {
        int u = (t >= o) ? sm[t - o] : 0;
        __syncthreads();
        sm[t] += u;
        __syncthreads();
    }
    if (t < n4) {
        int ex = sm[t] - s;
        rb[4 * t] = ex; cur[4 * t] = ex;
        rb[4 * t + 1] = ex + l0; cur[4 * t + 1] = ex + l0;
        rb[4 * t + 2] = ex + l0 + l1; cur[4 * t + 2] = ex + l0 + l1;
        rb[4 * t + 3] = ex + l0 + l1 + l2; cur[4 * t + 3] = ex + l0 + l1 + l2;
    }
    __syncthreads();
    int E = *pE;
    int ebase = blk * 8192;
    for (int it = 0; it < 32; it++) {
        int e = ebase + it * 256 + t;
        if (e < E) {
            int2 ed = edges[e];
            unsigned packed = ((unsigned)(ed.y & 127) << SB) | (unsigned)ed.x;
            int pos = atomicAdd(&cur[ed.y >> 7], 1);
            out[pos] = packed;
        }
    }
    __syncthreads();
    int w = t >> 6, lane = t & 63;
    for (int b = w; b < NB; b += 4) {
        int cb = c[b];
        if (cb == 0) continue;
        int gb = base[b * 256 + blk];
        int rbb = rb[b];
        for (int i = lane; i < cb; i += 64) seg[gb + i] = out[rbb + i];
    }
}
// one block per bucket: counting-sort by dlow, coalesced csrS write
__global__ void k_binC(const unsigned* __restrict__ seg, const int* __restrict__ rowS,
                       int* __restrict__ csrS, int bucketNodeBase0, int SB) {
    __shared__ unsigned raw[4096], srt[4096];
    __shared__ int h[128], cur[128];
    int b = blockIdx.x, t = threadIdx.x;
    int s0 = rowS[b * 128], s1 = rowS[b * 128 + 128];
    int n = s1 - s0;
    if (n > 4096) n = 4096; // 45-sigma guard (mean<=2048)
    for (int i = t; i < n; i += 256) raw[i] = seg[s0 + i];
    if (t < 128) h[t] = 0;
    __syncthreads();
    for (int i = t; i < n; i += 256) atomicAdd(&h[raw[i] >> SB], 1);
    __syncthreads();
    int v = (t < 128) ? h[t] : 0;
    // exclusive scan over 128 in shared
    for (int o = 1; o < 128; o <<= 1) {
        int u = (t < 128 && t >= o) ? h[t - o] : 0;
        __syncthreads();
        if (t < 128) h[t] += u;
        __syncthreads();
    }
    if (t < 128) cur[t] = h[t] - v;
    __syncthreads();
    unsigned mask = (1u << SB) - 1u;
    for (int i = t; i < n; i += 256) {
        unsigned r = raw[i];
        int p = atomicAdd(&cur[r >> SB], 1);
        srt[p] = r & mask;
    }
    __syncthreads();
    for (int i = t; i < n; i += 256) csrS[s0 + i] = (int)srt[i];
    (void)bucketNodeBase0;
}

// ---------- GCN aggregation + fused score (R11 paired-edge float4) ----------
__global__ void k_agg(const float4* __restrict__ xw, const int* __restrict__ rowS,
                      const int* __restrict__ csrS, const float* __restrict__ dis,
                      const float* __restrict__ bias, const float* __restrict__ pn,
                      float4* __restrict__ h, float* __restrict__ scores, int N) {
    int nb = gridDim.x;
    int bid = blockIdx.x;
    int sb = (bid & 7) * (nb >> 3) + (bid >> 3); // contiguous chunk per XCD
    int d = sb * 4 + (threadIdx.x >> 6);
    int lane = threadIdx.x & 63;
    int hl = lane >> 5;   // 0: even edges, 1: odd edges
    int l = lane & 31;    // float4 slot within row
    int rs = rowS[d], re = rowS[d + 1];
    float4 a = make_float4(0.f, 0.f, 0.f, 0.f);
    for (int j0 = rs; j0 < re; j0 += 64) {
        int myj = j0 + lane;
        int sV = (myj < re) ? csrS[myj] : 0;
        float dV = (myj < re) ? dis[sV] : 0.f;
        int c64 = re - j0; if (c64 > 64) c64 = 64;
        int j = 0;
        for (; j + 8 <= c64; j += 8) {
            int i0 = j + hl, i1 = j + 2 + hl, i2 = j + 4 + hl, i3 = j + 6 + hl;
            int s0 = __shfl(sV, i0), s1 = __shfl(sV, i1);
            int s2 = __shfl(sV, i2), s3 = __shfl(sV, i3);
            float d0 = __shfl(dV, i0), d1 = __shfl(dV, i1);
            float d2 = __shfl(dV, i2), d3 = __shfl(dV, i3);
            float4 v0 = xw[s0 * 32 + l];
            float4 v1 = xw[s1 * 32 + l];
            float4 v2 = xw[s2 * 32 + l];
            float4 v3 = xw[s3 * 32 + l];
            a.x = fmaf(d0, v0.x, a.x); a.y = fmaf(d0, v0.y, a.y);
            a.z = fmaf(d0, v0.z, a.z); a.w = fmaf(d0, v0.w, a.w);
            a.x = fmaf(d1, v1.x, a.x); a.y = fmaf(d1, v1.y, a.y);
            a.z = fmaf(d1, v1.z, a.z); a.w = fmaf(d1, v1.w, a.w);
            a.x = fmaf(d2, v2.x, a.x); a.y = fmaf(d2, v2.y, a.y);
            a.z = fmaf(d2, v2.z, a.z); a.w = fmaf(d2, v2.w, a.w);
            a.x = fmaf(d3, v3.x, a.x); a.y = fmaf(d3, v3.y, a.y);
            a.z = fmaf(d3, v3.z, a.z); a.w = fmaf(d3, v3.w, a.w);
        }
        for (; j < c64; j += 2) {
            int i = j + hl;
            int ic = (i < c64) ? i : (c64 - 1);
            int s = __shfl(sV, ic);
            float dd = __shfl(dV, ic);
            if (i >= c64) dd = 0.f;
            float4 v = xw[s * 32 + l];
            a.x = fmaf(dd, v.x, a.x); a.y = fmaf(dd, v.y, a.y);
            a.z = fmaf(dd, v.z, a.z); a.w = fmaf(dd, v.w, a.w);
        }
    }
    // combine even/odd halves (lanes L and L+32 hold same dims)
    a.x += __shfl_xor(a.x, 32);
    a.y += __shfl_xor(a.y, 32);
    a.z += __shfl_xor(a.z, 32);
    a.w += __shfl_xor(a.w, 32);
    float disd = dis[d];
    float invd = disd * disd; // 1/deg
    float4 xd = xw[d * 32 + l];
    float4 bv = ((const float4*)bias)[l];
    float4 r;
    r.x = disd * a.x + xd.x * invd + bv.x;
    r.y = disd * a.y + xd.y * invd + bv.y;
    r.z = disd * a.z + xd.z * invd + bv.z;
    r.w = disd * a.w + xd.w * invd + bv.w;
    r.x = r.x > 0.f ? r.x : 0.f;
    r.y = r.y > 0.f ? r.y : 0.f;
    r.z = r.z > 0.f ? r.z : 0.f;
    r.w = r.w > 0.f ? r.w : 0.f;
    if (hl == 0) h[d * 32 + l] = r;
    float4 pv = ((const float4*)pn)[l];
    float v = r.x * pv.x + r.y * pv.y + r.z * pv.z + r.w * pv.w;
    for (int o = 32; o > 0; o >>= 1) v += __shfl_down(v, o);
    if (lane == 0) scores[d] = tanhf(0.5f * v); // halves duplicated -> sum is 2x dot
}

// ---------- exact top-k per graph: map[old global] = new local idx or -1 ----------
__global__ void k_topk(const float* __restrict__ scores, int* __restrict__ map, int n, int k) {
    __shared__ unsigned keys[2048];
    __shared__ int sm[256];
    __shared__ int red[4];
    int b = blockIdx.x, t = threadIdx.x;
    const float* sc = scores + b * n;
    int m = n >> 8;

    for (int i = t; i < n; i += 256) keys[i] = f2o(sc[i]);
    __syncthreads();

    unsigned prefix = 0u;
    for (int bit = 31; bit >= 0; bit--) {
        unsigned trial = prefix | (1u << bit);
        int c = 0;
        for (int i = t; i < n; i += 256) c += (keys[i] >= trial) ? 1 : 0;
        for (int o = 32; o > 0; o >>= 1) c += __shfl_down(c, o);
        if ((t & 63) == 0) red[t >> 6] = c;
        __syncthreads();
        int tot = red[0] + red[1] + red[2] + red[3];
        __syncthreads();
        if (tot >= k) prefix = trial;
    }
    unsigned T = prefix;

    int c = 0;
    for (int i = t; i < n; i += 256) c += (keys[i] > T) ? 1 : 0;
    for (int o = 32; o > 0; o >>= 1) c += __shfl_down(c, o);
    if ((t & 63) == 0) red[t >> 6] = c;
    __syncthreads();
    int mEq = k - (red[0] + red[1] + red[2] + red[3]);
    __syncthreads();

    int base = t * m;
    int eqc = 0;
    for (int j = 0; j < m; j++) eqc += (keys[base + j] == T) ? 1 : 0;
    sm[t] = eqc;
    __syncthreads();
    for (int o = 1; o < 256; o <<= 1) {
        int u = (t >= o) ? sm[t - o] : 0;
        __syncthreads();
        sm[t] += u;
        __syncthreads();
    }
    int er = sm[t] - eqc;
    __syncthreads();

    unsigned kb = 0; int kc = 0;
    for (int j = 0; j < m; j++) {
        unsigned ky = keys[base + j];
        bool kp = (ky > T) || (ky == T && er < mEq);
        if (ky == T) er++;
        if (kp) { kb |= (1u << j); kc++; }
    }
    sm[t] = kc;
    __syncthreads();
    for (int o = 1; o < 256; o <<= 1) {
        int u = (t >= o) ? sm[t - o] : 0;
        __syncthreads();
        sm[t] += u;
        __syncthreads();
    }
    int nidx = sm[t] - kc;
    for (int j = 0; j < m; j++) {
        map[b * n + base + j] = ((kb >> j) & 1u) ? nidx++ : -1;
    }
}

// ---------- compact kept nodes: xn[g*k+new] = h[old] * score[old] ----------
__global__ void k_compact(const float* __restrict__ h, const float* __restrict__ scores,
                          const int* __restrict__ map, float* __restrict__ xn,
                          int N, int n, int k) {
    int wid = (blockIdx.x * 256 + threadIdx.x) >> 6;
    int lane = threadIdx.x & 63;
    int mi = map[wid];
    if (mi < 0) return;
    float s = scores[wid];
    int gg = wid / n;
    int dst = (gg * k + mi) * CF;
    xn[dst + lane]      = h[wid * CF + lane] * s;
    xn[dst + 64 + lane] = h[wid * CF + 64 + lane] * s;
}

// ---------- edge remap + compaction, atomic-free two-pass (R6) ----------
__global__ void k_remapA1(const int* __restrict__ g, const int* __restrict__ sl,
                          const int* __restrict__ dl, const int* __restrict__ map,
                          int* __restrict__ wcnt) {
    int e = blockIdx.x * 256 + threadIdx.x;
    int gg = g[e];
    bool valid = (map[gg * NN0 + sl[e]] >= 0) && (map[gg * NN0 + dl[e]] >= 0);
    unsigned long long mask = __ballot(valid);
    if ((threadIdx.x & 63) == 0) wcnt[e >> 6] = __popcll(mask);
}
__global__ void k_remapB1(const int* __restrict__ g, const int* __restrict__ sl,
                          const int* __restrict__ dl, const int* __restrict__ map,
                          const int* __restrict__ wbase, int2* __restrict__ eout,
                          int* __restrict__ pTot, int k) {
    int e = blockIdx.x * 256 + threadIdx.x;
    int lane = threadIdx.x & 63;
    int gg = g[e];
    int ns = map[gg * NN0 + sl[e]];
    int nd = map[gg * NN0 + dl[e]];
    bool valid = (ns >= 0 && nd >= 0);
    unsigned long long mask = __ballot(valid);
    if (valid) {
        int off = __popcll(mask & ((1ull << lane) - 1ull));
        eout[wbase[e >> 6] + off] = make_int2(gg * k + ns, gg * k + nd);
    }
    if (e == 0) pTot[0] = wbase[ET >> 6];
}
__global__ void k_remapA2(const int2* __restrict__ ein, const int* pE,
                          const int* __restrict__ map, int* __restrict__ wcnt) {
    int e = blockIdx.x * 256 + threadIdx.x;
    bool valid = false;
    if (e < *pE) {
        int2 ed = ein[e];
        valid = (map[ed.x] >= 0) && (map[ed.y] >= 0);
    }
    unsigned long long mask = __ballot(valid);
    if ((threadIdx.x & 63) == 0) wcnt[e >> 6] = __popcll(mask);
}
__global__ void k_remapB2(const int2* __restrict__ ein, const int* pE,
                          const int* __restrict__ map, const int* __restrict__ wbase,
                          int2* __restrict__ eout, int* __restrict__ pTot,
                          int n, int k) {
    int e = blockIdx.x * 256 + threadIdx.x;
    int lane = threadIdx.x & 63;
    bool valid = false;
    int gg = 0, ns = 0, nd = 0;
    if (e < *pE) {
        int2 ed = ein[e];
        ns = map[ed.x]; nd = map[ed.y];
        gg = ed.x / n;
        valid = (ns >= 0 && nd >= 0);
    }
    unsigned long long mask = __ballot(valid);
    if (valid) {
        int off = __popcll(mask & ((1ull << lane) - 1ull));
        eout[wbase[e >> 6] + off] = make_int2(gg * k + ns, gg * k + nd);
    }
    if (e == 0) pTot[0] = wbase[ET >> 6];
}

// ---------- fused layer-3 pool ----------
__global__ void k_pool3(const float* __restrict__ h, const float* __restrict__ scores,
                        const int* __restrict__ map, float* __restrict__ pooled) {
    int b = blockIdx.x, cthr = threadIdx.x; // 128 threads
    float acc = 0.f;
    for (int i = 0; i < 512; i++) {
        int gi = b * 512 + i;
        int mi = map[gi];
        if (mi >= 0) acc += h[gi * CF + cthr] * scores[gi];
    }
    pooled[b * CF + cthr] = acc;
}

// ---------- final MLP ----------
__global__ void k_mlp(const float* __restrict__ pooled, const float* __restrict__ Wm,
                      const float* __restrict__ bm, float* __restrict__ out) {
    int b = blockIdx.x, t = threadIdx.x;
    if (t < OUTF) {
        float acc = bm[t];
        for (int c2 = 0; c2 < CF; c2++) acc += pooled[b * CF + c2] * Wm[c2 * OUTF + t];
        out[b * OUTF + t] = acc;
    }
}

extern "C" void kernel_launch(void* const* d_in, const int* in_sizes, int n_in,
                              void* d_out, int out_size, void* d_ws, size_t ws_size,
                              hipStream_t stream) {
    const float* x  = (const float*)d_in[0];
    const int* sl   = (const int*)d_in[1];
    const int* dl   = (const int*)d_in[2];
    const int* g    = (const int*)d_in[3];
    const float* W1 = (const float*)d_in[4];
    const float* b1 = (const float*)d_in[5];
    const float* p1 = (const float*)d_in[6];
    const float* W2 = (const float*)d_in[7];
    const float* b2 = (const float*)d_in[8];
    const float* p2 = (const float*)d_in[9];
    const float* W3 = (const float*)d_in[10];
    const float* b3 = (const float*)d_in[11];
    const float* p3 = (const float*)d_in[12];
    const float* Wm = (const float*)d_in[13];
    const float* bm = (const float*)d_in[14];

    // workspace layout (~145.8 MB total, unchanged footprint)
    char* ws = (char*)d_ws;
    float* A    = (float*)(ws + 0);            // 64MB
    float* Bb   = (float*)(ws + 67108864ull);  // 64MB
    int*   csrS = (int*)  (ws + 134217728ull); // 8MB
    int*   cnt  = (int*)  (ws + 142606336ull); // 512KB
    int*   rowS = (int*)  (ws + 143130624ull); // 512KB+4
    int*   curs = (int*)  (ws + 143655168ull); // 512KB
    float* scor = (float*)(ws + 144179456ull); // 512KB
    int*   map  = (int*)  (ws + 144703744ull); // 512KB
    float* pn   = (float*)(ws + 145228032ull); // 1.5KB
    float* pool = (float*)(ws + 145230080ull); // 32KB
    int*   ecnt = (int*)  (ws + 145262848ull); // counters
    int*   part = (int*)  (ws + 145263104ull); // scan partials (<=129 ints)
    float* dis  = (float*)(ws + 145264640ull); // 512KB: per-node rsqrt(deg)

    // aliased regions (lifetimes verified):
    int2*  EA  = (int2*)(ws + 33554432ull);              // A[32:48MB], written AFTER agg1/compact1
    int2*  EB  = (int2*)(ws + 67108864ull);              // Bb[0:16MB]
    float* x2  = A;                                      // A[0:32MB]
    float* xw2 = Bb;                                     // Bb[0:32MB]
    float* h2  = A;                                      // A[0:32MB]
    float* x3  = (float*)(ws + 100663296ull);            // Bb[32:48MB]
    float* xw3 = A;                                      // A[0:16MB]
    float* h3  = Bb;                                     // Bb[0:16MB]
    int*   wcnt  = (int*)(ws + 50331648ull);             // A[48:64MB] region (post-agg1 only)
    int*   wbase = (int*)(ws + 50462720ull);
    // bucket-fill intermediates (time-disjoint holes):
    // R17: layer-1 trio must NOT live in A (xw1 = ALL of A until agg1 done).
    // Bb is dead until agg1 writes h1 -> safe for seg1/H1a/BSa.
    unsigned* seg1 = (unsigned*)(ws + 67108864ull);      // Bb[0:8MB]
    int*      H1a  = (int*)(ws + 75497472ull);           // Bb[8:9MB]
    int*      BSa  = (int*)(ws + 76546048ull);           // Bb[9:10MB]
    unsigned* seg2 = (unsigned*)(ws + 117440512ull);     // Bb[48:56MB] (dead h1)
    int*      H1b  = (int*)(ws + 125829120ull);          // Bb[56:56.5MB]
    int*      BSb  = (int*)(ws + 126877696ull);          // Bb[57:57.5MB]
    unsigned* seg3 = (unsigned*)(ws + 16777216ull);      // A[16:24MB] (dead h2, xw3=A[0:16MB])
    int*      H1c  = (int*)(ws + 25165824ull);           // A[24:24.25MB]
    int*      BSc  = (int*)(ws + 26214400ull);           // A[25:25.25MB]

    k_normp<<<3, 128, 0, stream>>>(p1, p2, p3, pn);

    // ================= layer 1 (N=131072, n=2048, k=1024) =================
    k_gemm<<<512, 256, 0, stream>>>(x, W1, A, 131072);
    hipMemsetAsync(cnt, 0, 524288, stream);
    k_hist1<<<8192, 256, 0, stream>>>(g, dl, cnt);
    k_ps1<<<128, 256, 0, stream>>>(cnt, part);
    k_ps2<<<1, 64, 0, stream>>>(part, 128);
    k_ps3<<<128, 256, 0, stream>>>(cnt, part, rowS, curs, dis, 131072);
    k_binA1<<<256, 256, 0, stream>>>(g, dl, H1a);
    k_scanB<<<1024, 256, 0, stream>>>(H1a, rowS, BSa, 1024);
    k_binB1<<<256, 256, 0, stream>>>(g, sl, dl, H1a, BSa, seg1);
    k_binC<<<1024, 256, 0, stream>>>(seg1, rowS, csrS, 0, 17);
    k_agg<<<32768, 256, 0, stream>>>((const float4*)A, rowS, csrS, dis, b1, pn, (float4*)Bb, scor, 131072);
    k_topk<<<64, 256, 0, stream>>>(scor, map, 2048, 1024);
    k_compact<<<32768, 256, 0, stream>>>(Bb, scor, map, x2, 131072, 2048, 1024);
    k_remapA1<<<8192, 256, 0, stream>>>(g, sl, dl, map, wcnt);
    k_ps1<<<32, 256, 0, stream>>>(wcnt, part);
    k_ps2<<<1, 64, 0, stream>>>(part, 32);
    k_ps3<<<32, 256, 0, stream>>>(wcnt, part, wbase, wbase, nullptr, 32768);
    k_remapB1<<<8192, 256, 0, stream>>>(g, sl, dl, map, wbase, EA, &ecnt[0], 1024);

    // ================= layer 2 (N=65536, n=1024, k=512) =================
    k_gemm<<<256, 256, 0, stream>>>(x2, W2, xw2, 65536);
    hipMemsetAsync(cnt, 0, 262144, stream);
    k_hist2<<<8192, 256, 0, stream>>>(EA, &ecnt[0], cnt);
    k_ps1<<<64, 256, 0, stream>>>(cnt, part);
    k_ps2<<<1, 64, 0, stream>>>(part, 64);
    k_ps3<<<64, 256, 0, stream>>>(cnt, part, rowS, curs, dis, 65536);
    k_binA2<<<256, 256, 0, stream>>>(EA, &ecnt[0], H1b, 512);
    k_scanB<<<512, 256, 0, stream>>>(H1b, rowS, BSb, 512);
    k_binB2<<<256, 256, 0, stream>>>(EA, &ecnt[0], H1b, BSb, seg2, 512, 16);
    k_binC<<<512, 256, 0, stream>>>(seg2, rowS, csrS, 0, 16);
    k_agg<<<16384, 256, 0, stream>>>((const float4*)xw2, rowS, csrS, dis, b2, pn + 128, (float4*)h2, scor, 65536);
    k_topk<<<64, 256, 0, stream>>>(scor, map, 1024, 512);
    k_compact<<<16384, 256, 0, stream>>>(h2, scor, map, x3, 65536, 1024, 512);
    k_remapA2<<<8192, 256, 0, stream>>>(EA, &ecnt[0], map, wcnt);
    k_ps1<<<32, 256, 0, stream>>>(wcnt, part);
    k_ps2<<<1, 64, 0, stream>>>(part, 32);
    k_ps3<<<32, 256, 0, stream>>>(wcnt, part, wbase, wbase, nullptr, 32768);
    k_remapB2<<<8192, 256, 0, stream>>>(EA, &ecnt[0], map, wbase, EB, &ecnt[1], 1024, 512);

    // ================= layer 3 (N=32768, n=512, k=256) =================
    k_gemm<<<128, 256, 0, stream>>>(x3, W3, xw3, 32768);
    hipMemsetAsync(cnt, 0, 131072, stream);
    k_hist2<<<8192, 256, 0, stream>>>(EB, &ecnt[1], cnt);
    k_ps1<<<32, 256, 0, stream>>>(cnt, part);
    k_ps2<<<1, 64, 0, stream>>>(part, 32);
    k_ps3<<<32, 256, 0, stream>>>(cnt, part, rowS, curs, dis, 32768);
    k_binA2<<<256, 256, 0, stream>>>(EB, &ecnt[1], H1c, 256);
    k_scanB<<<256, 256, 0, stream>>>(H1c, rowS, BSc, 256);
    k_binB2<<<256, 256, 0, stream>>>(EB, &ecnt[1], H1c, BSc, seg3, 256, 15);
    k_binC<<<256, 256, 0, stream>>>(seg3, rowS, csrS, 0, 15);
    k_agg<<<8192, 256, 0, stream>>>((const float4*)xw3, rowS, csrS, dis, b3, pn + 256, (float4*)h3, scor, 32768);
    k_topk<<<64, 256, 0, stream>>>(scor, map, 512, 256);
    k_pool3<<<64, 128, 0, stream>>>(h3, scor, map, pool);
    k_mlp<<<64, 64, 0, stream>>>(pool, Wm, bm, (float*)d_out);
}

// Round 18
// 814.732 us; speedup vs baseline: 1.1606x; 1.1606x over previous
//
#include <hip/hip_runtime.h>
#include <math.h>

#define BQ   64
#define NN0  2048
#define CF   128
#define ET   2097152
#define OUTF 16

// ---------- helpers ----------
static __device__ __forceinline__ unsigned f2o(float f) {
    unsigned u = __float_as_uint(f);
    return (u & 0x80000000u) ? ~u : (u | 0x80000000u);
}

// ---------- normalize p vectors ----------
__global__ void k_normp(const float* p1, const float* p2, const float* p3, float* pn) {
    const float* ps[3] = {p1, p2, p3};
    const float* p = ps[blockIdx.x];
    int t = threadIdx.x; // 128 threads
    float v = p[t];
    float s = v * v;
    for (int o = 32; o > 0; o >>= 1) s += __shfl_down(s, o);
    __shared__ float ws2[2];
    if ((t & 63) == 0) ws2[t >> 6] = s;
    __syncthreads();
    float tot = ws2[0] + ws2[1];
    pn[blockIdx.x * CF + t] = v / sqrtf(tot);
}

// ---------- GEMM: Y[N][128] = X[N][128] @ W[128][128], f32 ----------
__global__ __launch_bounds__(256, 2) void k_gemm(const float* __restrict__ X,
                                                 const float* __restrict__ W,
                                                 float* __restrict__ Y, int N) {
    __shared__ float xT[32][260];
    __shared__ float Wc[32][128];
    int t = threadIdx.x;
    int cg = t & 15, rg = t >> 4;
    int c0 = cg * 8, r0 = rg * 16;
    int rowBase = blockIdx.x * 256;

    float acc[16][8];
#pragma unroll
    for (int i = 0; i < 16; i++)
#pragma unroll
        for (int j = 0; j < 8; j++) acc[i][j] = 0.f;

    for (int kc = 0; kc < 4; kc++) {
        __syncthreads();
#pragma unroll
        for (int j = 0; j < 8; j++) {
            int id = t + 256 * j;
            int r = id >> 3;
            int k4 = id & 7;
            float4 v = *(const float4*)&X[(rowBase + r) * CF + kc * 32 + k4 * 4];
            int kk = k4 * 4;
            xT[kk + 0][r] = v.x; xT[kk + 1][r] = v.y;
            xT[kk + 2][r] = v.z; xT[kk + 3][r] = v.w;
        }
#pragma unroll
        for (int j = 0; j < 4; j++) {
            int id = t + 256 * j;
            int kk = id >> 5;
            int cc = (id & 31) * 4;
            *(float4*)&Wc[kk][cc] = *(const float4*)&W[(kc * 32 + kk) * CF + cc];
        }
        __syncthreads();
#pragma unroll 4
        for (int kk = 0; kk < 32; kk++) {
            float xr[16];
#pragma unroll
            for (int i = 0; i < 16; i += 4)
                *(float4*)&xr[i] = *(float4*)&xT[kk][r0 + i];
            float wv[8];
            *(float4*)&wv[0] = *(float4*)&Wc[kk][c0];
            *(float4*)&wv[4] = *(float4*)&Wc[kk][c0 + 4];
#pragma unroll
            for (int i = 0; i < 16; i++)
#pragma unroll
                for (int j = 0; j < 8; j++)
                    acc[i][j] = fmaf(xr[i], wv[j], acc[i][j]);
        }
    }
#pragma unroll
    for (int i = 0; i < 16; i++) {
        int r = rowBase + r0 + i;
        *(float4*)&Y[r * CF + c0]     = make_float4(acc[i][0], acc[i][1], acc[i][2], acc[i][3]);
        *(float4*)&Y[r * CF + c0 + 4] = make_float4(acc[i][4], acc[i][5], acc[i][6], acc[i][7]);
    }
}

// ---------- histograms ----------
__global__ void k_hist1(const int* __restrict__ g, const int* __restrict__ dl, int* cnt) {
    int e = blockIdx.x * 256 + threadIdx.x;
    if (e < ET) atomicAdd(&cnt[g[e] * NN0 + dl[e]], 1);
}
__global__ void k_hist2(const int2* __restrict__ edges, const int* pE, int* cnt) {
    int e = blockIdx.x * 256 + threadIdx.x;
    if (e < *pE) atomicAdd(&cnt[edges[e].y], 1);
}

// ---------- exclusive scan (3 kernels), chunk=1024 ----------
__global__ void k_ps1(const int* __restrict__ cnt, int* part) {
    int b = blockIdx.x, t = threadIdx.x;
    int base = b * 1024;
    int s = 0;
    for (int j = t; j < 1024; j += 256) s += cnt[base + j];
    for (int o = 32; o > 0; o >>= 1) s += __shfl_down(s, o);
    __shared__ int sm[4];
    if ((t & 63) == 0) sm[t >> 6] = s;
    __syncthreads();
    if (t == 0) part[b] = sm[0] + sm[1] + sm[2] + sm[3];
}
__global__ void k_ps2(int* part, int nb) {
    if (threadIdx.x == 0) {
        int run = 0;
        for (int i = 0; i < nb; i++) { int v = part[i]; part[i] = run; run += v; }
        part[nb] = run;
    }
}
// emits dis[i] = rsqrt(deg_i) (deg = cnt+1) for the agg pass.
__global__ void k_ps3(const int* __restrict__ cnt, const int* __restrict__ part,
                      int* rowS, int* curs, float* dis, int N) {
    __shared__ int sm[256];
    int b = blockIdx.x, t = threadIdx.x;
    int base = b * 1024;
    int loc[4], cv[4];
    int s = 0;
#pragma unroll
    for (int j = 0; j < 4; j++) { loc[j] = s; cv[j] = cnt[base + t * 4 + j]; s += cv[j]; }
    sm[t] = s;
    __syncthreads();
    for (int o = 1; o < 256; o <<= 1) {
        int u = (t >= o) ? sm[t - o] : 0;
        __syncthreads();
        sm[t] += u;
        __syncthreads();
    }
    int incl = sm[t];
    int thrBase = part[b] + incl - s;
#pragma unroll
    for (int j = 0; j < 4; j++) {
        int idx = base + t * 4 + j;
        rowS[idx] = thrBase + loc[j];
        curs[idx] = thrBase + loc[j];
        if (dis != nullptr) dis[idx] = rsqrtf((float)(cv[j] + 1));
    }
    if (b == gridDim.x - 1 && t == 255) rowS[N] = part[b] + incl;
}

// ---------- CSR fill, XCD-range-partitioned (R11 config = best measured) ----------
// R17 post-mortem: bucket-sort build was write-clean (15MB vs 142MB) but
// execution-shape-bound (1 block/CU, 8-elem wave flushes, LDS conflicts):
// 130us in binB alone vs 92us for this whole kernel. Reverted to R11.
// Known floor: scattered 4B stores ~15x write-amplified (structural).
__global__ void k_fill1(const int* __restrict__ g, const int* __restrict__ sl,
                        const int* __restrict__ dl, int* curs, int* csrS) {
    int r = blockIdx.x & 7;
    int base = (blockIdx.x >> 3) * 2048;
#pragma unroll
    for (int i = 0; i < 8; i++) {
        int e = base + i * 256 + threadIdx.x;
        int gg = g[e];
        int d = gg * NN0 + dl[e];
        if ((d >> 14) == r) {
            int pos = atomicAdd(&curs[d], 1);
            csrS[pos] = gg * NN0 + sl[e];
        }
    }
}
__global__ void k_fill2(const int2* __restrict__ edges, const int* pE,
                        int* curs, int* csrS, int shift) {
    int r = blockIdx.x & 7;
    int base = (blockIdx.x >> 3) * 2048;
    int E = *pE;
#pragma unroll
    for (int i = 0; i < 8; i++) {
        int e = base + i * 256 + threadIdx.x;
        if (e < E) {
            int2 ed = edges[e];
            if ((ed.y >> shift) == r) {
                int pos = atomicAdd(&curs[ed.y], 1);
                csrS[pos] = ed.x;
            }
        }
    }
}

// ---------- GCN aggregation + fused score (R11 paired-edge float4) ----------
__global__ void k_agg(const float4* __restrict__ xw, const int* __restrict__ rowS,
                      const int* __restrict__ csrS, const float* __restrict__ dis,
                      const float* __restrict__ bias, const float* __restrict__ pn,
                      float4* __restrict__ h, float* __restrict__ scores, int N) {
    int nb = gridDim.x;
    int bid = blockIdx.x;
    int sb = (bid & 7) * (nb >> 3) + (bid >> 3); // contiguous chunk per XCD
    int d = sb * 4 + (threadIdx.x >> 6);
    int lane = threadIdx.x & 63;
    int hl = lane >> 5;   // 0: even edges, 1: odd edges
    int l = lane & 31;    // float4 slot within row
    int rs = rowS[d], re = rowS[d + 1];
    float4 a = make_float4(0.f, 0.f, 0.f, 0.f);
    for (int j0 = rs; j0 < re; j0 += 64) {
        int myj = j0 + lane;
        int sV = (myj < re) ? csrS[myj] : 0;
        float dV = (myj < re) ? dis[sV] : 0.f;
        int c64 = re - j0; if (c64 > 64) c64 = 64;
        int j = 0;
        for (; j + 8 <= c64; j += 8) {
            int i0 = j + hl, i1 = j + 2 + hl, i2 = j + 4 + hl, i3 = j + 6 + hl;
            int s0 = __shfl(sV, i0), s1 = __shfl(sV, i1);
            int s2 = __shfl(sV, i2), s3 = __shfl(sV, i3);
            float d0 = __shfl(dV, i0), d1 = __shfl(dV, i1);
            float d2 = __shfl(dV, i2), d3 = __shfl(dV, i3);
            float4 v0 = xw[s0 * 32 + l];
            float4 v1 = xw[s1 * 32 + l];
            float4 v2 = xw[s2 * 32 + l];
            float4 v3 = xw[s3 * 32 + l];
            a.x = fmaf(d0, v0.x, a.x); a.y = fmaf(d0, v0.y, a.y);
            a.z = fmaf(d0, v0.z, a.z); a.w = fmaf(d0, v0.w, a.w);
            a.x = fmaf(d1, v1.x, a.x); a.y = fmaf(d1, v1.y, a.y);
            a.z = fmaf(d1, v1.z, a.z); a.w = fmaf(d1, v1.w, a.w);
            a.x = fmaf(d2, v2.x, a.x); a.y = fmaf(d2, v2.y, a.y);
            a.z = fmaf(d2, v2.z, a.z); a.w = fmaf(d2, v2.w, a.w);
            a.x = fmaf(d3, v3.x, a.x); a.y = fmaf(d3, v3.y, a.y);
            a.z = fmaf(d3, v3.z, a.z); a.w = fmaf(d3, v3.w, a.w);
        }
        for (; j < c64; j += 2) {
            int i = j + hl;
            int ic = (i < c64) ? i : (c64 - 1);
            int s = __shfl(sV, ic);
            float dd = __shfl(dV, ic);
            if (i >= c64) dd = 0.f;
            float4 v = xw[s * 32 + l];
            a.x = fmaf(dd, v.x, a.x); a.y = fmaf(dd, v.y, a.y);
            a.z = fmaf(dd, v.z, a.z); a.w = fmaf(dd, v.w, a.w);
        }
    }
    // combine even/odd halves (lanes L and L+32 hold same dims)
    a.x += __shfl_xor(a.x, 32);
    a.y += __shfl_xor(a.y, 32);
    a.z += __shfl_xor(a.z, 32);
    a.w += __shfl_xor(a.w, 32);
    float disd = dis[d];
    float invd = disd * disd; // 1/deg
    float4 xd = xw[d * 32 + l];
    float4 bv = ((const float4*)bias)[l];
    float4 r;
    r.x = disd * a.x + xd.x * invd + bv.x;
    r.y = disd * a.y + xd.y * invd + bv.y;
    r.z = disd * a.z + xd.z * invd + bv.z;
    r.w = disd * a.w + xd.w * invd + bv.w;
    r.x = r.x > 0.f ? r.x : 0.f;
    r.y = r.y > 0.f ? r.y : 0.f;
    r.z = r.z > 0.f ? r.z : 0.f;
    r.w = r.w > 0.f ? r.w : 0.f;
    if (hl == 0) h[d * 32 + l] = r;
    float4 pv = ((const float4*)pn)[l];
    float v = r.x * pv.x + r.y * pv.y + r.z * pv.z + r.w * pv.w;
    for (int o = 32; o > 0; o >>= 1) v += __shfl_down(v, o);
    if (lane == 0) scores[d] = tanhf(0.5f * v); // halves duplicated -> sum is 2x dot
}

// ---------- exact top-k per graph: map[old global] = new local idx or -1 ----------
__global__ void k_topk(const float* __restrict__ scores, int* __restrict__ map, int n, int k) {
    __shared__ unsigned keys[2048];
    __shared__ int sm[256];
    __shared__ int red[4];
    int b = blockIdx.x, t = threadIdx.x;
    const float* sc = scores + b * n;
    int m = n >> 8;

    for (int i = t; i < n; i += 256) keys[i] = f2o(sc[i]);
    __syncthreads();

    unsigned prefix = 0u;
    for (int bit = 31; bit >= 0; bit--) {
        unsigned trial = prefix | (1u << bit);
        int c = 0;
        for (int i = t; i < n; i += 256) c += (keys[i] >= trial) ? 1 : 0;
        for (int o = 32; o > 0; o >>= 1) c += __shfl_down(c, o);
        if ((t & 63) == 0) red[t >> 6] = c;
        __syncthreads();
        int tot = red[0] + red[1] + red[2] + red[3];
        __syncthreads();
        if (tot >= k) prefix = trial;
    }
    unsigned T = prefix;

    int c = 0;
    for (int i = t; i < n; i += 256) c += (keys[i] > T) ? 1 : 0;
    for (int o = 32; o > 0; o >>= 1) c += __shfl_down(c, o);
    if ((t & 63) == 0) red[t >> 6] = c;
    __syncthreads();
    int mEq = k - (red[0] + red[1] + red[2] + red[3]);
    __syncthreads();

    int base = t * m;
    int eqc = 0;
    for (int j = 0; j < m; j++) eqc += (keys[base + j] == T) ? 1 : 0;
    sm[t] = eqc;
    __syncthreads();
    for (int o = 1; o < 256; o <<= 1) {
        int u = (t >= o) ? sm[t - o] : 0;
        __syncthreads();
        sm[t] += u;
        __syncthreads();
    }
    int er = sm[t] - eqc;
    __syncthreads();

    unsigned kb = 0; int kc = 0;
    for (int j = 0; j < m; j++) {
        unsigned ky = keys[base + j];
        bool kp = (ky > T) || (ky == T && er < mEq);
        if (ky == T) er++;
        if (kp) { kb |= (1u << j); kc++; }
    }
    sm[t] = kc;
    __syncthreads();
    for (int o = 1; o < 256; o <<= 1) {
        int u = (t >= o) ? sm[t - o] : 0;
        __syncthreads();
        sm[t] += u;
        __syncthreads();
    }
    int nidx = sm[t] - kc;
    for (int j = 0; j < m; j++) {
        map[b * n + base + j] = ((kb >> j) & 1u) ? nidx++ : -1;
    }
}

// ---------- compact kept nodes: xn[g*k+new] = h[old] * score[old] ----------
__global__ void k_compact(const float* __restrict__ h, const float* __restrict__ scores,
                          const int* __restrict__ map, float* __restrict__ xn,
                          int N, int n, int k) {
    int wid = (blockIdx.x * 256 + threadIdx.x) >> 6;
    int lane = threadIdx.x & 63;
    int mi = map[wid];
    if (mi < 0) return;
    float s = scores[wid];
    int gg = wid / n;
    int dst = (gg * k + mi) * CF;
    xn[dst + lane]      = h[wid * CF + lane] * s;
    xn[dst + 64 + lane] = h[wid * CF + 64 + lane] * s;
}

// ---------- edge remap + compaction, atomic-free two-pass (R6) ----------
__global__ void k_remapA1(const int* __restrict__ g, const int* __restrict__ sl,
                          const int* __restrict__ dl, const int* __restrict__ map,
                          int* __restrict__ wcnt) {
    int e = blockIdx.x * 256 + threadIdx.x;
    int gg = g[e];
    bool valid = (map[gg * NN0 + sl[e]] >= 0) && (map[gg * NN0 + dl[e]] >= 0);
    unsigned long long mask = __ballot(valid);
    if ((threadIdx.x & 63) == 0) wcnt[e >> 6] = __popcll(mask);
}
__global__ void k_remapB1(const int* __restrict__ g, const int* __restrict__ sl,
                          const int* __restrict__ dl, const int* __restrict__ map,
                          const int* __restrict__ wbase, int2* __restrict__ eout,
                          int* __restrict__ pTot, int k) {
    int e = blockIdx.x * 256 + threadIdx.x;
    int lane = threadIdx.x & 63;
    int gg = g[e];
    int ns = map[gg * NN0 + sl[e]];
    int nd = map[gg * NN0 + dl[e]];
    bool valid = (ns >= 0 && nd >= 0);
    unsigned long long mask = __ballot(valid);
    if (valid) {
        int off = __popcll(mask & ((1ull << lane) - 1ull));
        eout[wbase[e >> 6] + off] = make_int2(gg * k + ns, gg * k + nd);
    }
    if (e == 0) pTot[0] = wbase[ET >> 6];
}
__global__ void k_remapA2(const int2* __restrict__ ein, const int* pE,
                          const int* __restrict__ map, int* __restrict__ wcnt) {
    int e = blockIdx.x * 256 + threadIdx.x;
    bool valid = false;
    if (e < *pE) {
        int2 ed = ein[e];
        valid = (map[ed.x] >= 0) && (map[ed.y] >= 0);
    }
    unsigned long long mask = __ballot(valid);
    if ((threadIdx.x & 63) == 0) wcnt[e >> 6] = __popcll(mask);
}
__global__ void k_remapB2(const int2* __restrict__ ein, const int* pE,
                          const int* __restrict__ map, const int* __restrict__ wbase,
                          int2* __restrict__ eout, int* __restrict__ pTot,
                          int n, int k) {
    int e = blockIdx.x * 256 + threadIdx.x;
    int lane = threadIdx.x & 63;
    bool valid = false;
    int gg = 0, ns = 0, nd = 0;
    if (e < *pE) {
        int2 ed = ein[e];
        ns = map[ed.x]; nd = map[ed.y];
        gg = ed.x / n;
        valid = (ns >= 0 && nd >= 0);
    }
    unsigned long long mask = __ballot(valid);
    if (valid) {
        int off = __popcll(mask & ((1ull << lane) - 1ull));
        eout[wbase[e >> 6] + off] = make_int2(gg * k + ns, gg * k + nd);
    }
    if (e == 0) pTot[0] = wbase[ET >> 6];
}

// ---------- fused layer-3 pool ----------
__global__ void k_pool3(const float* __restrict__ h, const float* __restrict__ scores,
                        const int* __restrict__ map, float* __restrict__ pooled) {
    int b = blockIdx.x, cthr = threadIdx.x; // 128 threads
    float acc = 0.f;
    for (int i = 0; i < 512; i++) {
        int gi = b * 512 + i;
        int mi = map[gi];
        if (mi >= 0) acc += h[gi * CF + cthr] * scores[gi];
    }
    pooled[b * CF + cthr] = acc;
}

// ---------- final MLP ----------
__global__ void k_mlp(const float* __restrict__ pooled, const float* __restrict__ Wm,
                      const float* __restrict__ bm, float* __restrict__ out) {
    int b = blockIdx.x, t = threadIdx.x;
    if (t < OUTF) {
        float acc = bm[t];
        for (int c2 = 0; c2 < CF; c2++) acc += pooled[b * CF + c2] * Wm[c2 * OUTF + t];
        out[b * OUTF + t] = acc;
    }
}

extern "C" void kernel_launch(void* const* d_in, const int* in_sizes, int n_in,
                              void* d_out, int out_size, void* d_ws, size_t ws_size,
                              hipStream_t stream) {
    const float* x  = (const float*)d_in[0];
    const int* sl   = (const int*)d_in[1];
    const int* dl   = (const int*)d_in[2];
    const int* g    = (const int*)d_in[3];
    const float* W1 = (const float*)d_in[4];
    const float* b1 = (const float*)d_in[5];
    const float* p1 = (const float*)d_in[6];
    const float* W2 = (const float*)d_in[7];
    const float* b2 = (const float*)d_in[8];
    const float* p2 = (const float*)d_in[9];
    const float* W3 = (const float*)d_in[10];
    const float* b3 = (const float*)d_in[11];
    const float* p3 = (const float*)d_in[12];
    const float* Wm = (const float*)d_in[13];
    const float* bm = (const float*)d_in[14];

    // workspace layout (~145.8 MB total)
    char* ws = (char*)d_ws;
    float* A    = (float*)(ws + 0);            // 64MB
    float* Bb   = (float*)(ws + 67108864ull);  // 64MB
    int*   csrS = (int*)  (ws + 134217728ull); // 8MB
    int*   cnt  = (int*)  (ws + 142606336ull); // 512KB
    int*   rowS = (int*)  (ws + 143130624ull); // 512KB+4
    int*   curs = (int*)  (ws + 143655168ull); // 512KB
    float* scor = (float*)(ws + 144179456ull); // 512KB
    int*   map  = (int*)  (ws + 144703744ull); // 512KB
    float* pn   = (float*)(ws + 145228032ull); // 1.5KB
    float* pool = (float*)(ws + 145230080ull); // 32KB
    int*   ecnt = (int*)  (ws + 145262848ull); // counters
    int*   part = (int*)  (ws + 145263104ull); // scan partials (<=129 ints)
    float* dis  = (float*)(ws + 145264640ull); // 512KB: per-node rsqrt(deg)

    // aliased regions (lifetimes verified):
    int2*  EA  = (int2*)(ws + 33554432ull);              // A[32:48MB]
    int2*  EB  = (int2*)(ws + 67108864ull);              // Bb[0:16MB]
    float* x2  = A;                                      // A[0:32MB]
    float* xw2 = Bb;                                     // Bb[0:32MB]
    float* h2  = A;                                      // A[0:32MB]
    float* x3  = (float*)(ws + 100663296ull);            // Bb[32:48MB]
    float* xw3 = A;                                      // A[0:16MB]
    float* h3  = Bb;                                     // Bb[0:16MB]
    int*   wcnt  = (int*)(ws + 50331648ull);             // A[48:64MB] region
    int*   wbase = (int*)(ws + 50462720ull);

    k_normp<<<3, 128, 0, stream>>>(p1, p2, p3, pn);

    // ================= layer 1 (N=131072, n=2048, k=1024) =================
    k_gemm<<<512, 256, 0, stream>>>(x, W1, A, 131072);
    hipMemsetAsync(cnt, 0, 524288, stream);
    k_hist1<<<8192, 256, 0, stream>>>(g, dl, cnt);
    k_ps1<<<128, 256, 0, stream>>>(cnt, part);
    k_ps2<<<1, 64, 0, stream>>>(part, 128);
    k_ps3<<<128, 256, 0, stream>>>(cnt, part, rowS, curs, dis, 131072);
    k_fill1<<<8192, 256, 0, stream>>>(g, sl, dl, curs, csrS);
    k_agg<<<32768, 256, 0, stream>>>((const float4*)A, rowS, csrS, dis, b1, pn, (float4*)Bb, scor, 131072);
    k_topk<<<64, 256, 0, stream>>>(scor, map, 2048, 1024);
    k_compact<<<32768, 256, 0, stream>>>(Bb, scor, map, x2, 131072, 2048, 1024);
    k_remapA1<<<8192, 256, 0, stream>>>(g, sl, dl, map, wcnt);
    k_ps1<<<32, 256, 0, stream>>>(wcnt, part);
    k_ps2<<<1, 64, 0, stream>>>(part, 32);
    k_ps3<<<32, 256, 0, stream>>>(wcnt, part, wbase, wbase, nullptr, 32768);
    k_remapB1<<<8192, 256, 0, stream>>>(g, sl, dl, map, wbase, EA, &ecnt[0], 1024);

    // ================= layer 2 (N=65536, n=1024, k=512) =================
    k_gemm<<<256, 256, 0, stream>>>(x2, W2, xw2, 65536);
    hipMemsetAsync(cnt, 0, 262144, stream);
    k_hist2<<<8192, 256, 0, stream>>>(EA, &ecnt[0], cnt);
    k_ps1<<<64, 256, 0, stream>>>(cnt, part);
    k_ps2<<<1, 64, 0, stream>>>(part, 64);
    k_ps3<<<64, 256, 0, stream>>>(cnt, part, rowS, curs, dis, 65536);
    k_fill2<<<8192, 256, 0, stream>>>(EA, &ecnt[0], curs, csrS, 13);
    k_agg<<<16384, 256, 0, stream>>>((const float4*)xw2, rowS, csrS, dis, b2, pn + 128, (float4*)h2, scor, 65536);
    k_topk<<<64, 256, 0, stream>>>(scor, map, 1024, 512);
    k_compact<<<16384, 256, 0, stream>>>(h2, scor, map, x3, 65536, 1024, 512);
    k_remapA2<<<8192, 256, 0, stream>>>(EA, &ecnt[0], map, wcnt);
    k_ps1<<<32, 256, 0, stream>>>(wcnt, part);
    k_ps2<<<1, 64, 0, stream>>>(part, 32);
    k_ps3<<<32, 256, 0, stream>>>(wcnt, part, wbase, wbase, nullptr, 32768);
    k_remapB2<<<8192, 256, 0, stream>>>(EA, &ecnt[0], map, wbase, EB, &ecnt[1], 1024, 512);

    // ================= layer 3 (N=32768, n=512, k=256) =================
    k_gemm<<<128, 256, 0, stream>>>(x3, W3, xw3, 32768);
    hipMemsetAsync(cnt, 0, 131072, stream);
    k_hist2<<<8192, 256, 0, stream>>>(EB, &ecnt[1], cnt);
    k_ps1<<<32, 256, 0, stream>>>(cnt, part);
    k_ps2<<<1, 64, 0, stream>>>(part, 32);
    k_ps3<<<32, 256, 0, stream>>>(cnt, part, rowS, curs, dis, 32768);
    k_fill2<<<8192, 256, 0, stream>>>(EB, &ecnt[1], curs, csrS, 12);
    k_agg<<<8192, 256, 0, stream>>>((const float4*)xw3, rowS, csrS, dis, b3, pn + 256, (float4*)h3, scor, 32768);
    k_topk<<<64, 256, 0, stream>>>(scor, map, 512, 256);
    k_pool3<<<64, 128, 0, stream>>>(h3, scor, map, pool);
    k_mlp<<<64, 64, 0, stream>>>(pool, Wm, bm, (float*)d_out);
}

// Round 20
// 789.450 us; speedup vs baseline: 1.1978x; 1.0320x over previous
//
#include <hip/hip_runtime.h>
#include <math.h>

#define BQ   64
#define NN0  2048
#define CF   128
#define ET   2097152
#define OUTF 16

// ---------- helpers ----------
static __device__ __forceinline__ unsigned f2o(float f) {
    unsigned u = __float_as_uint(f);
    return (u & 0x80000000u) ? ~u : (u | 0x80000000u);
}

// ---------- normalize p vectors ----------
__global__ void k_normp(const float* p1, const float* p2, const float* p3, float* pn) {
    const float* ps[3] = {p1, p2, p3};
    const float* p = ps[blockIdx.x];
    int t = threadIdx.x; // 128 threads
    float v = p[t];
    float s = v * v;
    for (int o = 32; o > 0; o >>= 1) s += __shfl_down(s, o);
    __shared__ float ws2[2];
    if ((t & 63) == 0) ws2[t >> 6] = s;
    __syncthreads();
    float tot = ws2[0] + ws2[1];
    pn[blockIdx.x * CF + t] = v / sqrtf(tot);
}

// ---------- GEMM: Y[N][128] = X[N][128] @ W[128][128], f32 ----------
__global__ __launch_bounds__(256, 2) void k_gemm(const float* __restrict__ X,
                                                 const float* __restrict__ W,
                                                 float* __restrict__ Y, int N) {
    __shared__ float xT[32][260];
    __shared__ float Wc[32][128];
    int t = threadIdx.x;
    int cg = t & 15, rg = t >> 4;
    int c0 = cg * 8, r0 = rg * 16;
    int rowBase = blockIdx.x * 256;

    float acc[16][8];
#pragma unroll
    for (int i = 0; i < 16; i++)
#pragma unroll
        for (int j = 0; j < 8; j++) acc[i][j] = 0.f;

    for (int kc = 0; kc < 4; kc++) {
        __syncthreads();
#pragma unroll
        for (int j = 0; j < 8; j++) {
            int id = t + 256 * j;
            int r = id >> 3;
            int k4 = id & 7;
            float4 v = *(const float4*)&X[(rowBase + r) * CF + kc * 32 + k4 * 4];
            int kk = k4 * 4;
            xT[kk + 0][r] = v.x; xT[kk + 1][r] = v.y;
            xT[kk + 2][r] = v.z; xT[kk + 3][r] = v.w;
        }
#pragma unroll
        for (int j = 0; j < 4; j++) {
            int id = t + 256 * j;
            int kk = id >> 5;
            int cc = (id & 31) * 4;
            *(float4*)&Wc[kk][cc] = *(const float4*)&W[(kc * 32 + kk) * CF + cc];
        }
        __syncthreads();
#pragma unroll 4
        for (int kk = 0; kk < 32; kk++) {
            float xr[16];
#pragma unroll
            for (int i = 0; i < 16; i += 4)
                *(float4*)&xr[i] = *(float4*)&xT[kk][r0 + i];
            float wv[8];
            *(float4*)&wv[0] = *(float4*)&Wc[kk][c0];
            *(float4*)&wv[4] = *(float4*)&Wc[kk][c0 + 4];
#pragma unroll
            for (int i = 0; i < 16; i++)
#pragma unroll
                for (int j = 0; j < 8; j++)
                    acc[i][j] = fmaf(xr[i], wv[j], acc[i][j]);
        }
    }
#pragma unroll
    for (int i = 0; i < 16; i++) {
        int r = rowBase + r0 + i;
        *(float4*)&Y[r * CF + c0]     = make_float4(acc[i][0], acc[i][1], acc[i][2], acc[i][3]);
        *(float4*)&Y[r * CF + c0 + 4] = make_float4(acc[i][4], acc[i][5], acc[i][6], acc[i][7]);
    }
}

// ---------- histograms ----------
__global__ void k_hist1(const int* __restrict__ g, const int* __restrict__ dl, int* cnt) {
    int e = blockIdx.x * 256 + threadIdx.x;
    if (e < ET) atomicAdd(&cnt[g[e] * NN0 + dl[e]], 1);
}
__global__ void k_hist2(const int2* __restrict__ edges, const int* pE, int* cnt) {
    int e = blockIdx.x * 256 + threadIdx.x;
    if (e < *pE) atomicAdd(&cnt[edges[e].y], 1);
}

// ---------- scans ----------
// R19: k_ps2 (single-thread serial prefix over chunk sums, ~5-10us latency x5
// calls) deleted. k_ps3f re-derives the part-prefix per block in LDS (<=128
// ints, ~1us, parallel). k_wscan fuses the whole 32768-int wcnt scan into one
// 1024-thread block (replaces ps1+ps2+ps3). 42 -> 35 graph nodes.
__global__ void k_ps1(const int* __restrict__ cnt, int* part) {
    int b = blockIdx.x, t = threadIdx.x;
    int base = b * 1024;
    int s = 0;
    for (int j = t; j < 1024; j += 256) s += cnt[base + j];
    for (int o = 32; o > 0; o >>= 1) s += __shfl_down(s, o);
    __shared__ int sm[4];
    if ((t & 63) == 0) sm[t >> 6] = s;
    __syncthreads();
    if (t == 0) part[b] = sm[0] + sm[1] + sm[2] + sm[3];
}
// emits dis[i] = rsqrt(deg_i) (deg = cnt+1) for the agg pass.
__global__ void k_ps3f(const int* __restrict__ cnt, const int* __restrict__ part,
                       int* rowS, int* curs, float* dis, int N, int nb) {
    __shared__ int pp[128];
    __shared__ int sm[256];
    int b = blockIdx.x, t = threadIdx.x;
    // local exclusive-prefix of part[0..nb) (nb <= 128)
    if (t < 128) pp[t] = (t < nb) ? part[t] : 0;
    __syncthreads();
    for (int o = 1; o < 128; o <<= 1) {
        int u = (t < 128 && t >= o) ? pp[t - o] : 0;
        __syncthreads();
        if (t < 128) pp[t] += u;
        __syncthreads();
    }
    int myBase = (b == 0) ? 0 : pp[b - 1];
    __syncthreads();

    int base = b * 1024;
    int loc[4], cv[4];
    int s = 0;
#pragma unroll
    for (int j = 0; j < 4; j++) { loc[j] = s; cv[j] = cnt[base + t * 4 + j]; s += cv[j]; }
    sm[t] = s;
    __syncthreads();
    for (int o = 1; o < 256; o <<= 1) {
        int u = (t >= o) ? sm[t - o] : 0;
        __syncthreads();
        sm[t] += u;
        __syncthreads();
    }
    int incl = sm[t];
    int thrBase = myBase + incl - s;
#pragma unroll
    for (int j = 0; j < 4; j++) {
        int idx = base + t * 4 + j;
        rowS[idx] = thrBase + loc[j];
        curs[idx] = thrBase + loc[j];
        if (dis != nullptr) dis[idx] = rsqrtf((float)(cv[j] + 1));
    }
    if (b == gridDim.x - 1 && t == 255) rowS[N] = myBase + incl;
}
// single-block exclusive scan of wcnt[32768] -> wbase[0..32768]
__global__ void k_wscan(const int* __restrict__ wcnt, int* __restrict__ wbase) {
    __shared__ int sm[1024];
    int t = threadIdx.x;
    int base = t * 32;
    int v[32];
    int s = 0;
#pragma unroll
    for (int j = 0; j < 32; j++) { v[j] = s; s += wcnt[base + j]; }
    sm[t] = s;
    __syncthreads();
    for (int o = 1; o < 1024; o <<= 1) {
        int u = (t >= o) ? sm[t - o] : 0;
        __syncthreads();
        sm[t] += u;
        __syncthreads();
    }
    int ex = sm[t] - s;
#pragma unroll
    for (int j = 0; j < 32; j++) wbase[base + j] = ex + v[j];
    if (t == 1023) wbase[32768] = sm[1023];
}

// ---------- CSR fill, XCD-range-partitioned (R11 config = best measured) ----------
__global__ void k_fill1(const int* __restrict__ g, const int* __restrict__ sl,
                        const int* __restrict__ dl, int* curs, int* csrS) {
    int r = blockIdx.x & 7;
    int base = (blockIdx.x >> 3) * 2048;
#pragma unroll
    for (int i = 0; i < 8; i++) {
        int e = base + i * 256 + threadIdx.x;
        int gg = g[e];
        int d = gg * NN0 + dl[e];
        if ((d >> 14) == r) {
            int pos = atomicAdd(&curs[d], 1);
            csrS[pos] = gg * NN0 + sl[e];
        }
    }
}
__global__ void k_fill2(const int2* __restrict__ edges, const int* pE,
                        int* curs, int* csrS, int shift) {
    int r = blockIdx.x & 7;
    int base = (blockIdx.x >> 3) * 2048;
    int E = *pE;
#pragma unroll
    for (int i = 0; i < 8; i++) {
        int e = base + i * 256 + threadIdx.x;
        if (e < E) {
            int2 ed = edges[e];
            if ((ed.y >> shift) == r) {
                int pos = atomicAdd(&curs[ed.y], 1);
                csrS[pos] = ed.x;
            }
        }
    }
}

// ---------- GCN aggregation + fused score (R11 paired-edge float4) ----------
__global__ void k_agg(const float4* __restrict__ xw, const int* __restrict__ rowS,
                      const int* __restrict__ csrS, const float* __restrict__ dis,
                      const float* __restrict__ bias, const float* __restrict__ pn,
                      float4* __restrict__ h, float* __restrict__ scores, int N) {
    int nb = gridDim.x;
    int bid = blockIdx.x;
    int sb = (bid & 7) * (nb >> 3) + (bid >> 3); // contiguous chunk per XCD
    int d = sb * 4 + (threadIdx.x >> 6);
    int lane = threadIdx.x & 63;
    int hl = lane >> 5;   // 0: even edges, 1: odd edges
    int l = lane & 31;    // float4 slot within row
    int rs = rowS[d], re = rowS[d + 1];
    float4 a = make_float4(0.f, 0.f, 0.f, 0.f);
    for (int j0 = rs; j0 < re; j0 += 64) {
        int myj = j0 + lane;
        int sV = (myj < re) ? csrS[myj] : 0;
        float dV = (myj < re) ? dis[sV] : 0.f;
        int c64 = re - j0; if (c64 > 64) c64 = 64;
        int j = 0;
        for (; j + 8 <= c64; j += 8) {
            int i0 = j + hl, i1 = j + 2 + hl, i2 = j + 4 + hl, i3 = j + 6 + hl;
            int s0 = __shfl(sV, i0), s1 = __shfl(sV, i1);
            int s2 = __shfl(sV, i2), s3 = __shfl(sV, i3);
            float d0 = __shfl(dV, i0), d1 = __shfl(dV, i1);
            float d2 = __shfl(dV, i2), d3 = __shfl(dV, i3);
            float4 v0 = xw[s0 * 32 + l];
            float4 v1 = xw[s1 * 32 + l];
            float4 v2 = xw[s2 * 32 + l];
            float4 v3 = xw[s3 * 32 + l];
            a.x = fmaf(d0, v0.x, a.x); a.y = fmaf(d0, v0.y, a.y);
            a.z = fmaf(d0, v0.z, a.z); a.w = fmaf(d0, v0.w, a.w);
            a.x = fmaf(d1, v1.x, a.x); a.y = fmaf(d1, v1.y, a.y);
            a.z = fmaf(d1, v1.z, a.z); a.w = fmaf(d1, v1.w, a.w);
            a.x = fmaf(d2, v2.x, a.x); a.y = fmaf(d2, v2.y, a.y);
            a.z = fmaf(d2, v2.z, a.z); a.w = fmaf(d2, v2.w, a.w);
            a.x = fmaf(d3, v3.x, a.x); a.y = fmaf(d3, v3.y, a.y);
            a.z = fmaf(d3, v3.z, a.z); a.w = fmaf(d3, v3.w, a.w);
        }
        for (; j < c64; j += 2) {
            int i = j + hl;
            int ic = (i < c64) ? i : (c64 - 1);
            int s = __shfl(sV, ic);
            float dd = __shfl(dV, ic);
            if (i >= c64) dd = 0.f;
            float4 v = xw[s * 32 + l];
            a.x = fmaf(dd, v.x, a.x); a.y = fmaf(dd, v.y, a.y);
            a.z = fmaf(dd, v.z, a.z); a.w = fmaf(dd, v.w, a.w);
        }
    }
    // combine even/odd halves (lanes L and L+32 hold same dims)
    a.x += __shfl_xor(a.x, 32);
    a.y += __shfl_xor(a.y, 32);
    a.z += __shfl_xor(a.z, 32);
    a.w += __shfl_xor(a.w, 32);
    float disd = dis[d];
    float invd = disd * disd; // 1/deg
    float4 xd = xw[d * 32 + l];
    float4 bv = ((const float4*)bias)[l];
    float4 r;
    r.x = disd * a.x + xd.x * invd + bv.x;
    r.y = disd * a.y + xd.y * invd + bv.y;
    r.z = disd * a.z + xd.z * invd + bv.z;
    r.w = disd * a.w + xd.w * invd + bv.w;
    r.x = r.x > 0.f ? r.x : 0.f;
    r.y = r.y > 0.f ? r.y : 0.f;
    r.z = r.z > 0.f ? r.z : 0.f;
    r.w = r.w > 0.f ? r.w : 0.f;
    if (hl == 0) h[d * 32 + l] = r;
    float4 pv = ((const float4*)pn)[l];
    float v = r.x * pv.x + r.y * pv.y + r.z * pv.z + r.w * pv.w;
    for (int o = 32; o > 0; o >>= 1) v += __shfl_down(v, o);
    if (lane == 0) scores[d] = tanhf(0.5f * v); // halves duplicated -> sum is 2x dot
}

// ---------- exact top-k per graph: map[old global] = new local idx or -1 ----------
__global__ void k_topk(const float* __restrict__ scores, int* __restrict__ map, int n, int k) {
    __shared__ unsigned keys[2048];
    __shared__ int sm[256];
    __shared__ int red[4];
    int b = blockIdx.x, t = threadIdx.x;
    const float* sc = scores + b * n;
    int m = n >> 8;

    for (int i = t; i < n; i += 256) keys[i] = f2o(sc[i]);
    __syncthreads();

    unsigned prefix = 0u;
    for (int bit = 31; bit >= 0; bit--) {
        unsigned trial = prefix | (1u << bit);
        int c = 0;
        for (int i = t; i < n; i += 256) c += (keys[i] >= trial) ? 1 : 0;
        for (int o = 32; o > 0; o >>= 1) c += __shfl_down(c, o);
        if ((t & 63) == 0) red[t >> 6] = c;
        __syncthreads();
        int tot = red[0] + red[1] + red[2] + red[3];
        __syncthreads();
        if (tot >= k) prefix = trial;
    }
    unsigned T = prefix;

    int c = 0;
    for (int i = t; i < n; i += 256) c += (keys[i] > T) ? 1 : 0;
    for (int o = 32; o > 0; o >>= 1) c += __shfl_down(c, o);
    if ((t & 63) == 0) red[t >> 6] = c;
    __syncthreads();
    int mEq = k - (red[0] + red[1] + red[2] + red[3]);
    __syncthreads();

    int base = t * m;
    int eqc = 0;
    for (int j = 0; j < m; j++) eqc += (keys[base + j] == T) ? 1 : 0;
    sm[t] = eqc;
    __syncthreads();
    for (int o = 1; o < 256; o <<= 1) {
        int u = (t >= o) ? sm[t - o] : 0;
        __syncthreads();
        sm[t] += u;
        __syncthreads();
    }
    int er = sm[t] - eqc;
    __syncthreads();

    unsigned kb = 0; int kc = 0;
    for (int j = 0; j < m; j++) {
        unsigned ky = keys[base + j];
        bool kp = (ky > T) || (ky == T && er < mEq);
        if (ky == T) er++;
        if (kp) { kb |= (1u << j); kc++; }
    }
    sm[t] = kc;
    __syncthreads();
    for (int o = 1; o < 256; o <<= 1) {
        int u = (t >= o) ? sm[t - o] : 0;
        __syncthreads();
        sm[t] += u;
        __syncthreads();
    }
    int nidx = sm[t] - kc;
    for (int j = 0; j < m; j++) {
        map[b * n + base + j] = ((kb >> j) & 1u) ? nidx++ : -1;
    }
}

// ---------- compact kept nodes: xn[g*k+new] = h[old] * score[old] ----------
__global__ void k_compact(const float* __restrict__ h, const float* __restrict__ scores,
                          const int* __restrict__ map, float* __restrict__ xn,
                          int N, int n, int k) {
    int wid = (blockIdx.x * 256 + threadIdx.x) >> 6;
    int lane = threadIdx.x & 63;
    int mi = map[wid];
    if (mi < 0) return;
    float s = scores[wid];
    int gg = wid / n;
    int dst = (gg * k + mi) * CF;
    xn[dst + lane]      = h[wid * CF + lane] * s;
    xn[dst + 64 + lane] = h[wid * CF + 64 + lane] * s;
}

// ---------- edge remap + compaction, atomic-free two-pass (R6) ----------
__global__ void k_remapA1(const int* __restrict__ g, const int* __restrict__ sl,
                          const int* __restrict__ dl, const int* __restrict__ map,
                          int* __restrict__ wcnt) {
    int e = blockIdx.x * 256 + threadIdx.x;
    int gg = g[e];
    bool valid = (map[gg * NN0 + sl[e]] >= 0) && (map[gg * NN0 + dl[e]] >= 0);
    unsigned long long mask = __ballot(valid);
    if ((threadIdx.x & 63) == 0) wcnt[e >> 6] = __popcll(mask);
}
__global__ void k_remapB1(const int* __restrict__ g, const int* __restrict__ sl,
                          const int* __restrict__ dl, const int* __restrict__ map,
                          const int* __restrict__ wbase, int2* __restrict__ eout,
                          int* __restrict__ pTot, int k) {
    int e = blockIdx.x * 256 + threadIdx.x;
    int lane = threadIdx.x & 63;
    int gg = g[e];
    int ns = map[gg * NN0 + sl[e]];
    int nd = map[gg * NN0 + dl[e]];
    bool valid = (ns >= 0 && nd >= 0);
    unsigned long long mask = __ballot(valid);
    if (valid) {
        int off = __popcll(mask & ((1ull << lane) - 1ull));
        eout[wbase[e >> 6] + off] = make_int2(gg * k + ns, gg * k + nd);
    }
    if (e == 0) pTot[0] = wbase[ET >> 6];
}
__global__ void k_remapA2(const int2* __restrict__ ein, const int* pE,
                          const int* __restrict__ map, int* __restrict__ wcnt) {
    int e = blockIdx.x * 256 + threadIdx.x;
    bool valid = false;
    if (e < *pE) {
        int2 ed = ein[e];
        valid = (map[ed.x] >= 0) && (map[ed.y] >= 0);
    }
    unsigned long long mask = __ballot(valid);
    if ((threadIdx.x & 63) == 0) wcnt[e >> 6] = __popcll(mask);
}
__global__ void k_remapB2(const int2* __restrict__ ein, const int* pE,
                          const int* __restrict__ map, const int* __restrict__ wbase,
                          int2* __restrict__ eout, int* __restrict__ pTot,
                          int n, int k) {
    int e = blockIdx.x * 256 + threadIdx.x;
    int lane = threadIdx.x & 63;
    bool valid = false;
    int gg = 0, ns = 0, nd = 0;
    if (e < *pE) {
        int2 ed = ein[e];
        ns = map[ed.x]; nd = map[ed.y];
        gg = ed.x / n;
        valid = (ns >= 0 && nd >= 0);
    }
    unsigned long long mask = __ballot(valid);
    if (valid) {
        int off = __popcll(mask & ((1ull << lane) - 1ull));
        eout[wbase[e >> 6] + off] = make_int2(gg * k + ns, gg * k + nd);
    }
    if (e == 0) pTot[0] = wbase[ET >> 6];
}

// ---------- fused layer-3 pool ----------
__global__ void k_pool3(const float* __restrict__ h, const float* __restrict__ scores,
                        const int* __restrict__ map, float* __restrict__ pooled) {
    int b = blockIdx.x, cthr = threadIdx.x; // 128 threads
    float acc = 0.f;
    for (int i = 0; i < 512; i++) {
        int gi = b * 512 + i;
        int mi = map[gi];
        if (mi >= 0) acc += h[gi * CF + cthr] * scores[gi];
    }
    pooled[b * CF + cthr] = acc;
}

// ---------- final MLP ----------
__global__ void k_mlp(const float* __restrict__ pooled, const float* __restrict__ Wm,
                      const float* __restrict__ bm, float* __restrict__ out) {
    int b = blockIdx.x, t = threadIdx.x;
    if (t < OUTF) {
        float acc = bm[t];
        for (int c2 = 0; c2 < CF; c2++) acc += pooled[b * CF + c2] * Wm[c2 * OUTF + t];
        out[b * OUTF + t] = acc;
    }
}

extern "C" void kernel_launch(void* const* d_in, const int* in_sizes, int n_in,
                              void* d_out, int out_size, void* d_ws, size_t ws_size,
                              hipStream_t stream) {
    const float* x  = (const float*)d_in[0];
    const int* sl   = (const int*)d_in[1];
    const int* dl   = (const int*)d_in[2];
    const int* g    = (const int*)d_in[3];
    const float* W1 = (const float*)d_in[4];
    const float* b1 = (const float*)d_in[5];
    const float* p1 = (const float*)d_in[6];
    const float* W2 = (const float*)d_in[7];
    const float* b2 = (const float*)d_in[8];
    const float* p2 = (const float*)d_in[9];
    const float* W3 = (const float*)d_in[10];
    const float* b3 = (const float*)d_in[11];
    const float* p3 = (const float*)d_in[12];
    const float* Wm = (const float*)d_in[13];
    const float* bm = (const float*)d_in[14];

    // workspace layout (~145.8 MB total)
    char* ws = (char*)d_ws;
    float* A    = (float*)(ws + 0);            // 64MB
    float* Bb   = (float*)(ws + 67108864ull);  // 64MB
    int*   csrS = (int*)  (ws + 134217728ull); // 8MB
    int*   cnt  = (int*)  (ws + 142606336ull); // 512KB
    int*   rowS = (int*)  (ws + 143130624ull); // 512KB+4
    int*   curs = (int*)  (ws + 143655168ull); // 512KB
    float* scor = (float*)(ws + 144179456ull); // 512KB
    int*   map  = (int*)  (ws + 144703744ull); // 512KB
    float* pn   = (float*)(ws + 145228032ull); // 1.5KB
    float* pool = (float*)(ws + 145230080ull); // 32KB
    int*   ecnt = (int*)  (ws + 145262848ull); // counters
    int*   part = (int*)  (ws + 145263104ull); // scan partials (<=129 ints)
    float* dis  = (float*)(ws + 145264640ull); // 512KB: per-node rsqrt(deg)

    // aliased regions (lifetimes verified):
    int2*  EA  = (int2*)(ws + 33554432ull);              // A[32:48MB]
    int2*  EB  = (int2*)(ws + 67108864ull);              // Bb[0:16MB]
    float* x2  = A;                                      // A[0:32MB]
    float* xw2 = Bb;                                     // Bb[0:32MB]
    float* h2  = A;                                      // A[0:32MB]
    float* x3  = (float*)(ws + 100663296ull);            // Bb[32:48MB]
    float* xw3 = A;                                      // A[0:16MB]
    float* h3  = Bb;                                     // Bb[0:16MB]
    int*   wcnt  = (int*)(ws + 50331648ull);             // A[48:64MB] region
    int*   wbase = (int*)(ws + 50462720ull);

    k_normp<<<3, 128, 0, stream>>>(p1, p2, p3, pn);

    // ================= layer 1 (N=131072, n=2048, k=1024) =================
    k_gemm<<<512, 256, 0, stream>>>(x, W1, A, 131072);
    hipMemsetAsync(cnt, 0, 524288, stream);
    k_hist1<<<8192, 256, 0, stream>>>(g, dl, cnt);
    k_ps1<<<128, 256, 0, stream>>>(cnt, part);
    k_ps3f<<<128, 256, 0, stream>>>(cnt, part, rowS, curs, dis, 131072, 128);
    k_fill1<<<8192, 256, 0, stream>>>(g, sl, dl, curs, csrS);
    k_agg<<<32768, 256, 0, stream>>>((const float4*)A, rowS, csrS, dis, b1, pn, (float4*)Bb, scor, 131072);
    k_topk<<<64, 256, 0, stream>>>(scor, map, 2048, 1024);
    k_compact<<<32768, 256, 0, stream>>>(Bb, scor, map, x2, 131072, 2048, 1024);
    k_remapA1<<<8192, 256, 0, stream>>>(g, sl, dl, map, wcnt);
    k_wscan<<<1, 1024, 0, stream>>>(wcnt, wbase);
    k_remapB1<<<8192, 256, 0, stream>>>(g, sl, dl, map, wbase, EA, &ecnt[0], 1024);

    // ================= layer 2 (N=65536, n=1024, k=512) =================
    k_gemm<<<256, 256, 0, stream>>>(x2, W2, xw2, 65536);
    hipMemsetAsync(cnt, 0, 262144, stream);
    k_hist2<<<8192, 256, 0, stream>>>(EA, &ecnt[0], cnt);
    k_ps1<<<64, 256, 0, stream>>>(cnt, part);
    k_ps3f<<<64, 256, 0, stream>>>(cnt, part, rowS, curs, dis, 65536, 64);
    k_fill2<<<8192, 256, 0, stream>>>(EA, &ecnt[0], curs, csrS, 13);
    k_agg<<<16384, 256, 0, stream>>>((const float4*)xw2, rowS, csrS, dis, b2, pn + 128, (float4*)h2, scor, 65536);
    k_topk<<<64, 256, 0, stream>>>(scor, map, 1024, 512);
    k_compact<<<16384, 256, 0, stream>>>(h2, scor, map, x3, 65536, 1024, 512);
    k_remapA2<<<8192, 256, 0, stream>>>(EA, &ecnt[0], map, wcnt);
    k_wscan<<<1, 1024, 0, stream>>>(wcnt, wbase);
    k_remapB2<<<8192, 256, 0, stream>>>(EA, &ecnt[0], map, wbase, EB, &ecnt[1], 1024, 512);

    // ================= layer 3 (N=32768, n=512, k=256) =================
    k_gemm<<<128, 256, 0, stream>>>(x3, W3, xw3, 32768);
    hipMemsetAsync(cnt, 0, 131072, stream);
    k_hist2<<<8192, 256, 0, stream>>>(EB, &ecnt[1], cnt);
    k_ps1<<<32, 256, 0, stream>>>(cnt, part);
    k_ps3f<<<32, 256, 0, stream>>>(cnt, part, rowS, curs, dis, 32768, 32);
    k_fill2<<<8192, 256, 0, stream>>>(EB, &ecnt[1], curs, csrS, 12);
    k_agg<<<8192, 256, 0, stream>>>((const float4*)xw3, rowS, csrS, dis, b3, pn + 256, (float4*)h3, scor, 32768);
    k_topk<<<64, 256, 0, stream>>>(scor, map, 512, 256);
    k_pool3<<<64, 128, 0, stream>>>(h3, scor, map, pool);
    k_mlp<<<64, 64, 0, stream>>>(pool, Wm, bm, (float*)d_out);
}

// Round 21
// 748.529 us; speedup vs baseline: 1.2632x; 1.0547x over previous
//
#include <hip/hip_runtime.h>
#include <math.h>

#define BQ   64
#define NN0  2048
#define CF   128
#define ET   2097152
#define OUTF 16

// ---------- helpers ----------
static __device__ __forceinline__ unsigned f2o(float f) {
    unsigned u = __float_as_uint(f);
    return (u & 0x80000000u) ? ~u : (u | 0x80000000u);
}

// ---------- normalize p vectors ----------
__global__ void k_normp(const float* p1, const float* p2, const float* p3, float* pn) {
    const float* ps[3] = {p1, p2, p3};
    const float* p = ps[blockIdx.x];
    int t = threadIdx.x; // 128 threads
    float v = p[t];
    float s = v * v;
    for (int o = 32; o > 0; o >>= 1) s += __shfl_down(s, o);
    __shared__ float ws2[2];
    if ((t & 63) == 0) ws2[t >> 6] = s;
    __syncthreads();
    float tot = ws2[0] + ws2[1];
    pn[blockIdx.x * CF + t] = v / sqrtf(tot);
}

// ---------- GEMM: Y[N][128] = X[N][128] @ W[128][128], f32 ----------
__global__ __launch_bounds__(256, 2) void k_gemm(const float* __restrict__ X,
                                                 const float* __restrict__ W,
                                                 float* __restrict__ Y, int N) {
    __shared__ float xT[32][260];
    __shared__ float Wc[32][128];
    int t = threadIdx.x;
    int cg = t & 15, rg = t >> 4;
    int c0 = cg * 8, r0 = rg * 16;
    int rowBase = blockIdx.x * 256;

    float acc[16][8];
#pragma unroll
    for (int i = 0; i < 16; i++)
#pragma unroll
        for (int j = 0; j < 8; j++) acc[i][j] = 0.f;

    for (int kc = 0; kc < 4; kc++) {
        __syncthreads();
#pragma unroll
        for (int j = 0; j < 8; j++) {
            int id = t + 256 * j;
            int r = id >> 3;
            int k4 = id & 7;
            float4 v = *(const float4*)&X[(rowBase + r) * CF + kc * 32 + k4 * 4];
            int kk = k4 * 4;
            xT[kk + 0][r] = v.x; xT[kk + 1][r] = v.y;
            xT[kk + 2][r] = v.z; xT[kk + 3][r] = v.w;
        }
#pragma unroll
        for (int j = 0; j < 4; j++) {
            int id = t + 256 * j;
            int kk = id >> 5;
            int cc = (id & 31) * 4;
            *(float4*)&Wc[kk][cc] = *(const float4*)&W[(kc * 32 + kk) * CF + cc];
        }
        __syncthreads();
#pragma unroll 4
        for (int kk = 0; kk < 32; kk++) {
            float xr[16];
#pragma unroll
            for (int i = 0; i < 16; i += 4)
                *(float4*)&xr[i] = *(float4*)&xT[kk][r0 + i];
            float wv[8];
            *(float4*)&wv[0] = *(float4*)&Wc[kk][c0];
            *(float4*)&wv[4] = *(float4*)&Wc[kk][c0 + 4];
#pragma unroll
            for (int i = 0; i < 16; i++)
#pragma unroll
                for (int j = 0; j < 8; j++)
                    acc[i][j] = fmaf(xr[i], wv[j], acc[i][j]);
        }
    }
#pragma unroll
    for (int i = 0; i < 16; i++) {
        int r = rowBase + r0 + i;
        *(float4*)&Y[r * CF + c0]     = make_float4(acc[i][0], acc[i][1], acc[i][2], acc[i][3]);
        *(float4*)&Y[r * CF + c0 + 4] = make_float4(acc[i][4], acc[i][5], acc[i][6], acc[i][7]);
    }
}

// ---------- gather-GEMM (R21): Y[new][:] = (scor[old] * H[old][:]) @ W ----------
// Replaces k_compact + k_gemm pair: topk emits keep[new]=old; rows gathered
// during LDS staging (512B rows stay 128B-coalesced), scaled by score inline.
__global__ __launch_bounds__(256, 2) void k_gemmG(const float* __restrict__ H,
                                                  const int* __restrict__ keep,
                                                  const float* __restrict__ scor,
                                                  const float* __restrict__ W,
                                                  float* __restrict__ Y) {
    __shared__ float xT[32][260];
    __shared__ float Wc[32][128];
    int t = threadIdx.x;
    int cg = t & 15, rg = t >> 4;
    int c0 = cg * 8, r0 = rg * 16;
    int rowBase = blockIdx.x * 256;

    float acc[16][8];
#pragma unroll
    for (int i = 0; i < 16; i++)
#pragma unroll
        for (int j = 0; j < 8; j++) acc[i][j] = 0.f;

    for (int kc = 0; kc < 4; kc++) {
        __syncthreads();
#pragma unroll
        for (int j = 0; j < 8; j++) {
            int id = t + 256 * j;
            int r = id >> 3;
            int k4 = id & 7;
            int old = keep[rowBase + r];
            float sc = scor[old];
            float4 v = *(const float4*)&H[old * CF + kc * 32 + k4 * 4];
            int kk = k4 * 4;
            xT[kk + 0][r] = v.x * sc; xT[kk + 1][r] = v.y * sc;
            xT[kk + 2][r] = v.z * sc; xT[kk + 3][r] = v.w * sc;
        }
#pragma unroll
        for (int j = 0; j < 4; j++) {
            int id = t + 256 * j;
            int kk = id >> 5;
            int cc = (id & 31) * 4;
            *(float4*)&Wc[kk][cc] = *(const float4*)&W[(kc * 32 + kk) * CF + cc];
        }
        __syncthreads();
#pragma unroll 4
        for (int kk = 0; kk < 32; kk++) {
            float xr[16];
#pragma unroll
            for (int i = 0; i < 16; i += 4)
                *(float4*)&xr[i] = *(float4*)&xT[kk][r0 + i];
            float wv[8];
            *(float4*)&wv[0] = *(float4*)&Wc[kk][c0];
            *(float4*)&wv[4] = *(float4*)&Wc[kk][c0 + 4];
#pragma unroll
            for (int i = 0; i < 16; i++)
#pragma unroll
                for (int j = 0; j < 8; j++)
                    acc[i][j] = fmaf(xr[i], wv[j], acc[i][j]);
        }
    }
#pragma unroll
    for (int i = 0; i < 16; i++) {
        int r = rowBase + r0 + i;
        *(float4*)&Y[r * CF + c0]     = make_float4(acc[i][0], acc[i][1], acc[i][2], acc[i][3]);
        *(float4*)&Y[r * CF + c0 + 4] = make_float4(acc[i][4], acc[i][5], acc[i][6], acc[i][7]);
    }
}

// ---------- histograms ----------
__global__ void k_hist1(const int* __restrict__ g, const int* __restrict__ dl, int* cnt) {
    int e = blockIdx.x * 256 + threadIdx.x;
    if (e < ET) atomicAdd(&cnt[g[e] * NN0 + dl[e]], 1);
}
__global__ void k_hist2(const int2* __restrict__ edges, const int* pE, int* cnt) {
    int e = blockIdx.x * 256 + threadIdx.x;
    if (e < *pE) atomicAdd(&cnt[edges[e].y], 1);
}

// ---------- scans (R19 fused forms) ----------
__global__ void k_ps1(const int* __restrict__ cnt, int* part) {
    int b = blockIdx.x, t = threadIdx.x;
    int base = b * 1024;
    int s = 0;
    for (int j = t; j < 1024; j += 256) s += cnt[base + j];
    for (int o = 32; o > 0; o >>= 1) s += __shfl_down(s, o);
    __shared__ int sm[4];
    if ((t & 63) == 0) sm[t >> 6] = s;
    __syncthreads();
    if (t == 0) part[b] = sm[0] + sm[1] + sm[2] + sm[3];
}
__global__ void k_ps3f(const int* __restrict__ cnt, const int* __restrict__ part,
                       int* rowS, int* curs, float* dis, int N, int nb) {
    __shared__ int pp[128];
    __shared__ int sm[256];
    int b = blockIdx.x, t = threadIdx.x;
    if (t < 128) pp[t] = (t < nb) ? part[t] : 0;
    __syncthreads();
    for (int o = 1; o < 128; o <<= 1) {
        int u = (t < 128 && t >= o) ? pp[t - o] : 0;
        __syncthreads();
        if (t < 128) pp[t] += u;
        __syncthreads();
    }
    int myBase = (b == 0) ? 0 : pp[b - 1];
    __syncthreads();

    int base = b * 1024;
    int loc[4], cv[4];
    int s = 0;
#pragma unroll
    for (int j = 0; j < 4; j++) { loc[j] = s; cv[j] = cnt[base + t * 4 + j]; s += cv[j]; }
    sm[t] = s;
    __syncthreads();
    for (int o = 1; o < 256; o <<= 1) {
        int u = (t >= o) ? sm[t - o] : 0;
        __syncthreads();
        sm[t] += u;
        __syncthreads();
    }
    int incl = sm[t];
    int thrBase = myBase + incl - s;
#pragma unroll
    for (int j = 0; j < 4; j++) {
        int idx = base + t * 4 + j;
        rowS[idx] = thrBase + loc[j];
        curs[idx] = thrBase + loc[j];
        if (dis != nullptr) dis[idx] = rsqrtf((float)(cv[j] + 1));
    }
    if (b == gridDim.x - 1 && t == 255) rowS[N] = myBase + incl;
}
__global__ void k_wscan(const int* __restrict__ wcnt, int* __restrict__ wbase) {
    __shared__ int sm[1024];
    int t = threadIdx.x;
    int base = t * 32;
    int v[32];
    int s = 0;
#pragma unroll
    for (int j = 0; j < 32; j++) { v[j] = s; s += wcnt[base + j]; }
    sm[t] = s;
    __syncthreads();
    for (int o = 1; o < 1024; o <<= 1) {
        int u = (t >= o) ? sm[t - o] : 0;
        __syncthreads();
        sm[t] += u;
        __syncthreads();
    }
    int ex = sm[t] - s;
#pragma unroll
    for (int j = 0; j < 32; j++) wbase[base + j] = ex + v[j];
    if (t == 1023) wbase[32768] = sm[1023];
}

// ---------- CSR fill, XCD-range-partitioned (R11 config = best measured) ----------
__global__ void k_fill1(const int* __restrict__ g, const int* __restrict__ sl,
                        const int* __restrict__ dl, int* curs, int* csrS) {
    int r = blockIdx.x & 7;
    int base = (blockIdx.x >> 3) * 2048;
#pragma unroll
    for (int i = 0; i < 8; i++) {
        int e = base + i * 256 + threadIdx.x;
        int gg = g[e];
        int d = gg * NN0 + dl[e];
        if ((d >> 14) == r) {
            int pos = atomicAdd(&curs[d], 1);
            csrS[pos] = gg * NN0 + sl[e];
        }
    }
}
__global__ void k_fill2(const int2* __restrict__ edges, const int* pE,
                        int* curs, int* csrS, int shift) {
    int r = blockIdx.x & 7;
    int base = (blockIdx.x >> 3) * 2048;
    int E = *pE;
#pragma unroll
    for (int i = 0; i < 8; i++) {
        int e = base + i * 256 + threadIdx.x;
        if (e < E) {
            int2 ed = edges[e];
            if ((ed.y >> shift) == r) {
                int pos = atomicAdd(&curs[ed.y], 1);
                csrS[pos] = ed.x;
            }
        }
    }
}

// ---------- GCN aggregation + fused score (R11 paired-edge float4) ----------
__global__ void k_agg(const float4* __restrict__ xw, const int* __restrict__ rowS,
                      const int* __restrict__ csrS, const float* __restrict__ dis,
                      const float* __restrict__ bias, const float* __restrict__ pn,
                      float4* __restrict__ h, float* __restrict__ scores, int N) {
    int nb = gridDim.x;
    int bid = blockIdx.x;
    int sb = (bid & 7) * (nb >> 3) + (bid >> 3); // contiguous chunk per XCD
    int d = sb * 4 + (threadIdx.x >> 6);
    int lane = threadIdx.x & 63;
    int hl = lane >> 5;   // 0: even edges, 1: odd edges
    int l = lane & 31;    // float4 slot within row
    int rs = rowS[d], re = rowS[d + 1];
    float4 a = make_float4(0.f, 0.f, 0.f, 0.f);
    for (int j0 = rs; j0 < re; j0 += 64) {
        int myj = j0 + lane;
        int sV = (myj < re) ? csrS[myj] : 0;
        float dV = (myj < re) ? dis[sV] : 0.f;
        int c64 = re - j0; if (c64 > 64) c64 = 64;
        int j = 0;
        for (; j + 8 <= c64; j += 8) {
            int i0 = j + hl, i1 = j + 2 + hl, i2 = j + 4 + hl, i3 = j + 6 + hl;
            int s0 = __shfl(sV, i0), s1 = __shfl(sV, i1);
            int s2 = __shfl(sV, i2), s3 = __shfl(sV, i3);
            float d0 = __shfl(dV, i0), d1 = __shfl(dV, i1);
            float d2 = __shfl(dV, i2), d3 = __shfl(dV, i3);
            float4 v0 = xw[s0 * 32 + l];
            float4 v1 = xw[s1 * 32 + l];
            float4 v2 = xw[s2 * 32 + l];
            float4 v3 = xw[s3 * 32 + l];
            a.x = fmaf(d0, v0.x, a.x); a.y = fmaf(d0, v0.y, a.y);
            a.z = fmaf(d0, v0.z, a.z); a.w = fmaf(d0, v0.w, a.w);
            a.x = fmaf(d1, v1.x, a.x); a.y = fmaf(d1, v1.y, a.y);
            a.z = fmaf(d1, v1.z, a.z); a.w = fmaf(d1, v1.w, a.w);
            a.x = fmaf(d2, v2.x, a.x); a.y = fmaf(d2, v2.y, a.y);
            a.z = fmaf(d2, v2.z, a.z); a.w = fmaf(d2, v2.w, a.w);
            a.x = fmaf(d3, v3.x, a.x); a.y = fmaf(d3, v3.y, a.y);
            a.z = fmaf(d3, v3.z, a.z); a.w = fmaf(d3, v3.w, a.w);
        }
        for (; j < c64; j += 2) {
            int i = j + hl;
            int ic = (i < c64) ? i : (c64 - 1);
            int s = __shfl(sV, ic);
            float dd = __shfl(dV, ic);
            if (i >= c64) dd = 0.f;
            float4 v = xw[s * 32 + l];
            a.x = fmaf(dd, v.x, a.x); a.y = fmaf(dd, v.y, a.y);
            a.z = fmaf(dd, v.z, a.z); a.w = fmaf(dd, v.w, a.w);
        }
    }
    // combine even/odd halves (lanes L and L+32 hold same dims)
    a.x += __shfl_xor(a.x, 32);
    a.y += __shfl_xor(a.y, 32);
    a.z += __shfl_xor(a.z, 32);
    a.w += __shfl_xor(a.w, 32);
    float disd = dis[d];
    float invd = disd * disd; // 1/deg
    float4 xd = xw[d * 32 + l];
    float4 bv = ((const float4*)bias)[l];
    float4 r;
    r.x = disd * a.x + xd.x * invd + bv.x;
    r.y = disd * a.y + xd.y * invd + bv.y;
    r.z = disd * a.z + xd.z * invd + bv.z;
    r.w = disd * a.w + xd.w * invd + bv.w;
    r.x = r.x > 0.f ? r.x : 0.f;
    r.y = r.y > 0.f ? r.y : 0.f;
    r.z = r.z > 0.f ? r.z : 0.f;
    r.w = r.w > 0.f ? r.w : 0.f;
    if (hl == 0) h[d * 32 + l] = r;
    float4 pv = ((const float4*)pn)[l];
    float v = r.x * pv.x + r.y * pv.y + r.z * pv.z + r.w * pv.w;
    for (int o = 32; o > 0; o >>= 1) v += __shfl_down(v, o);
    if (lane == 0) scores[d] = tanhf(0.5f * v); // halves duplicated -> sum is 2x dot
}

// ---------- exact top-k per graph (R21: also emits keep[new]=old global id) ----------
__global__ void k_topk(const float* __restrict__ scores, int* __restrict__ map,
                       int* __restrict__ keep, int n, int k) {
    __shared__ unsigned keys[2048];
    __shared__ int sm[256];
    __shared__ int red[4];
    int b = blockIdx.x, t = threadIdx.x;
    const float* sc = scores + b * n;
    int m = n >> 8;

    for (int i = t; i < n; i += 256) keys[i] = f2o(sc[i]);
    __syncthreads();

    unsigned prefix = 0u;
    for (int bit = 31; bit >= 0; bit--) {
        unsigned trial = prefix | (1u << bit);
        int c = 0;
        for (int i = t; i < n; i += 256) c += (keys[i] >= trial) ? 1 : 0;
        for (int o = 32; o > 0; o >>= 1) c += __shfl_down(c, o);
        if ((t & 63) == 0) red[t >> 6] = c;
        __syncthreads();
        int tot = red[0] + red[1] + red[2] + red[3];
        __syncthreads();
        if (tot >= k) prefix = trial;
    }
    unsigned T = prefix;

    int c = 0;
    for (int i = t; i < n; i += 256) c += (keys[i] > T) ? 1 : 0;
    for (int o = 32; o > 0; o >>= 1) c += __shfl_down(c, o);
    if ((t & 63) == 0) red[t >> 6] = c;
    __syncthreads();
    int mEq = k - (red[0] + red[1] + red[2] + red[3]);
    __syncthreads();

    int base = t * m;
    int eqc = 0;
    for (int j = 0; j < m; j++) eqc += (keys[base + j] == T) ? 1 : 0;
    sm[t] = eqc;
    __syncthreads();
    for (int o = 1; o < 256; o <<= 1) {
        int u = (t >= o) ? sm[t - o] : 0;
        __syncthreads();
        sm[t] += u;
        __syncthreads();
    }
    int er = sm[t] - eqc;
    __syncthreads();

    unsigned kb = 0; int kc = 0;
    for (int j = 0; j < m; j++) {
        unsigned ky = keys[base + j];
        bool kp = (ky > T) || (ky == T && er < mEq);
        if (ky == T) er++;
        if (kp) { kb |= (1u << j); kc++; }
    }
    sm[t] = kc;
    __syncthreads();
    for (int o = 1; o < 256; o <<= 1) {
        int u = (t >= o) ? sm[t - o] : 0;
        __syncthreads();
        sm[t] += u;
        __syncthreads();
    }
    int nidx = sm[t] - kc;
    for (int j = 0; j < m; j++) {
        if ((kb >> j) & 1u) {
            keep[b * k + nidx] = b * n + base + j;
            map[b * n + base + j] = nidx++;
        } else {
            map[b * n + base + j] = -1;
        }
    }
}

// ---------- edge remap + compaction, atomic-free two-pass (R6) ----------
__global__ void k_remapA1(const int* __restrict__ g, const int* __restrict__ sl,
                          const int* __restrict__ dl, const int* __restrict__ map,
                          int* __restrict__ wcnt) {
    int e = blockIdx.x * 256 + threadIdx.x;
    int gg = g[e];
    bool valid = (map[gg * NN0 + sl[e]] >= 0) && (map[gg * NN0 + dl[e]] >= 0);
    unsigned long long mask = __ballot(valid);
    if ((threadIdx.x & 63) == 0) wcnt[e >> 6] = __popcll(mask);
}
__global__ void k_remapB1(const int* __restrict__ g, const int* __restrict__ sl,
                          const int* __restrict__ dl, const int* __restrict__ map,
                          const int* __restrict__ wbase, int2* __restrict__ eout,
                          int* __restrict__ pTot, int k) {
    int e = blockIdx.x * 256 + threadIdx.x;
    int lane = threadIdx.x & 63;
    int gg = g[e];
    int ns = map[gg * NN0 + sl[e]];
    int nd = map[gg * NN0 + dl[e]];
    bool valid = (ns >= 0 && nd >= 0);
    unsigned long long mask = __ballot(valid);
    if (valid) {
        int off = __popcll(mask & ((1ull << lane) - 1ull));
        eout[wbase[e >> 6] + off] = make_int2(gg * k + ns, gg * k + nd);
    }
    if (e == 0) pTot[0] = wbase[ET >> 6];
}
__global__ void k_remapA2(const int2* __restrict__ ein, const int* pE,
                          const int* __restrict__ map, int* __restrict__ wcnt) {
    int e = blockIdx.x * 256 + threadIdx.x;
    bool valid = false;
    if (e < *pE) {
        int2 ed = ein[e];
        valid = (map[ed.x] >= 0) && (map[ed.y] >= 0);
    }
    unsigned long long mask = __ballot(valid);
    if ((threadIdx.x & 63) == 0) wcnt[e >> 6] = __popcll(mask);
}
__global__ void k_remapB2(const int2* __restrict__ ein, const int* pE,
                          const int* __restrict__ map, const int* __restrict__ wbase,
                          int2* __restrict__ eout, int* __restrict__ pTot,
                          int n, int k) {
    int e = blockIdx.x * 256 + threadIdx.x;
    int lane = threadIdx.x & 63;
    bool valid = false;
    int gg = 0, ns = 0, nd = 0;
    if (e < *pE) {
        int2 ed = ein[e];
        ns = map[ed.x]; nd = map[ed.y];
        gg = ed.x / n;
        valid = (ns >= 0 && nd >= 0);
    }
    unsigned long long mask = __ballot(valid);
    if (valid) {
        int off = __popcll(mask & ((1ull << lane) - 1ull));
        eout[wbase[e >> 6] + off] = make_int2(gg * k + ns, gg * k + nd);
    }
    if (e == 0) pTot[0] = wbase[ET >> 6];
}

// ---------- fused layer-3 pool ----------
__global__ void k_pool3(const float* __restrict__ h, const float* __restrict__ scores,
                        const int* __restrict__ map, float* __restrict__ pooled) {
    int b = blockIdx.x, cthr = threadIdx.x; // 128 threads
    float acc = 0.f;
    for (int i = 0; i < 512; i++) {
        int gi = b * 512 + i;
        int mi = map[gi];
        if (mi >= 0) acc += h[gi * CF + cthr] * scores[gi];
    }
    pooled[b * CF + cthr] = acc;
}

// ---------- final MLP ----------
__global__ void k_mlp(const float* __restrict__ pooled, const float* __restrict__ Wm,
                      const float* __restrict__ bm, float* __restrict__ out) {
    int b = blockIdx.x, t = threadIdx.x;
    if (t < OUTF) {
        float acc = bm[t];
        for (int c2 = 0; c2 < CF; c2++) acc += pooled[b * CF + c2] * Wm[c2 * OUTF + t];
        out[b * OUTF + t] = acc;
    }
}

extern "C" void kernel_launch(void* const* d_in, const int* in_sizes, int n_in,
                              void* d_out, int out_size, void* d_ws, size_t ws_size,
                              hipStream_t stream) {
    const float* x  = (const float*)d_in[0];
    const int* sl   = (const int*)d_in[1];
    const int* dl   = (const int*)d_in[2];
    const int* g    = (const int*)d_in[3];
    const float* W1 = (const float*)d_in[4];
    const float* b1 = (const float*)d_in[5];
    const float* p1 = (const float*)d_in[6];
    const float* W2 = (const float*)d_in[7];
    const float* b2 = (const float*)d_in[8];
    const float* p2 = (const float*)d_in[9];
    const float* W3 = (const float*)d_in[10];
    const float* b3 = (const float*)d_in[11];
    const float* p3 = (const float*)d_in[12];
    const float* Wm = (const float*)d_in[13];
    const float* bm = (const float*)d_in[14];

    // workspace layout (~145.8 MB total)
    char* ws = (char*)d_ws;
    float* A    = (float*)(ws + 0);            // 64MB
    float* Bb   = (float*)(ws + 67108864ull);  // 64MB
    int*   csrS = (int*)  (ws + 134217728ull); // 8MB
    int*   cnt  = (int*)  (ws + 142606336ull); // 512KB
    int*   rowS = (int*)  (ws + 143130624ull); // 512KB+4
    int*   curs = (int*)  (ws + 143655168ull); // 512KB
    float* scor = (float*)(ws + 144179456ull); // 512KB
    int*   map  = (int*)  (ws + 144703744ull); // 512KB
    float* pn   = (float*)(ws + 145228032ull); // 1.5KB
    float* pool = (float*)(ws + 145230080ull); // 32KB
    int*   ecnt = (int*)  (ws + 145262848ull); // counters
    int*   part = (int*)  (ws + 145263104ull); // scan partials (<=129 ints)
    float* dis  = (float*)(ws + 145264640ull); // 512KB: per-node rsqrt(deg)

    // R21 buffer plan (compact deleted; gather-gemm):
    //   xw1 = A[0:64]          h1 = Bb[0:64]
    //   EA  = A[32:48]  (written remapB1, after agg1 read xw1)
    //   xw2 = A[0:32]          h2 = Bb[0:32]  (h1 dead after gemmG2)
    //   EB  = Bb[32:48] (written remapB2, h1-upper dead)
    //   xw3 = A[0:16]          h3 = Bb[0:16]  (h2 dead after gemmG3)
    //   wcnt/wbase/keep in A[48:64] (xw1 dead there after agg1)
    int2*  EA  = (int2*)(ws + 33554432ull);              // A[32:48MB]
    int2*  EB  = (int2*)(ws + 100663296ull);             // Bb[32:48MB]
    float* xw2 = A;                                      // A[0:32MB]
    float* h2  = Bb;                                     // Bb[0:32MB]
    float* xw3 = A;                                      // A[0:16MB]
    float* h3  = Bb;                                     // Bb[0:16MB]
    int*   wcnt  = (int*)(ws + 50331648ull);             // A[48MB], 128KB
    int*   wbase = (int*)(ws + 50462720ull);             // 128KB+4
    int*   keep  = (int*)(ws + 50724864ull);             // 256KB (<= 65536 ints)

    k_normp<<<3, 128, 0, stream>>>(p1, p2, p3, pn);

    // ================= layer 1 (N=131072, n=2048, k=1024) =================
    k_gemm<<<512, 256, 0, stream>>>(x, W1, A, 131072);
    hipMemsetAsync(cnt, 0, 524288, stream);
    k_hist1<<<8192, 256, 0, stream>>>(g, dl, cnt);
    k_ps1<<<128, 256, 0, stream>>>(cnt, part);
    k_ps3f<<<128, 256, 0, stream>>>(cnt, part, rowS, curs, dis, 131072, 128);
    k_fill1<<<8192, 256, 0, stream>>>(g, sl, dl, curs, csrS);
    k_agg<<<32768, 256, 0, stream>>>((const float4*)A, rowS, csrS, dis, b1, pn, (float4*)Bb, scor, 131072);
    k_topk<<<64, 256, 0, stream>>>(scor, map, keep, 2048, 1024);
    k_remapA1<<<8192, 256, 0, stream>>>(g, sl, dl, map, wcnt);
    k_wscan<<<1, 1024, 0, stream>>>(wcnt, wbase);
    k_remapB1<<<8192, 256, 0, stream>>>(g, sl, dl, map, wbase, EA, &ecnt[0], 1024);

    // ================= layer 2 (N=65536, n=1024, k=512) =================
    k_gemmG<<<256, 256, 0, stream>>>(Bb, keep, scor, W2, xw2);
    hipMemsetAsync(cnt, 0, 262144, stream);
    k_hist2<<<8192, 256, 0, stream>>>(EA, &ecnt[0], cnt);
    k_ps1<<<64, 256, 0, stream>>>(cnt, part);
    k_ps3f<<<64, 256, 0, stream>>>(cnt, part, rowS, curs, dis, 65536, 64);
    k_fill2<<<8192, 256, 0, stream>>>(EA, &ecnt[0], curs, csrS, 13);
    k_agg<<<16384, 256, 0, stream>>>((const float4*)xw2, rowS, csrS, dis, b2, pn + 128, (float4*)h2, scor, 65536);
    k_topk<<<64, 256, 0, stream>>>(scor, map, keep, 1024, 512);
    k_remapA2<<<8192, 256, 0, stream>>>(EA, &ecnt[0], map, wcnt);
    k_wscan<<<1, 1024, 0, stream>>>(wcnt, wbase);
    k_remapB2<<<8192, 256, 0, stream>>>(EA, &ecnt[0], map, wbase, EB, &ecnt[1], 1024, 512);

    // ================= layer 3 (N=32768, n=512, k=256) =================
    k_gemmG<<<128, 256, 0, stream>>>(h2, keep, scor, W3, xw3);
    hipMemsetAsync(cnt, 0, 131072, stream);
    k_hist2<<<8192, 256, 0, stream>>>(EB, &ecnt[1], cnt);
    k_ps1<<<32, 256, 0, stream>>>(cnt, part);
    k_ps3f<<<32, 256, 0, stream>>>(cnt, part, rowS, curs, dis, 32768, 32);
    k_fill2<<<8192, 256, 0, stream>>>(EB, &ecnt[1], curs, csrS, 12);
    k_agg<<<8192, 256, 0, stream>>>((const float4*)xw3, rowS, csrS, dis, b3, pn + 256, (float4*)h3, scor, 32768);
    k_topk<<<64, 256, 0, stream>>>(scor, map, keep, 512, 256);
    k_pool3<<<64, 128, 0, stream>>>(h3, scor, map, pool);
    k_mlp<<<64, 64, 0, stream>>>(pool, Wm, bm, (float*)d_out);
}